// Round 8
// baseline (490.127 us; speedup 1.0000x reference)
//
#include <hip/hip_runtime.h>

typedef unsigned short ushort_t;
typedef __attribute__((ext_vector_type(4))) float f32x4;
typedef __attribute__((ext_vector_type(8))) short s16x8;
typedef __attribute__((ext_vector_type(4))) short s16x4;

#define SB 8388608   // x batch stride (512*16*32*32)
#define SC 16384     // x channel stride (16*32*32)
#define SF 1024      // x frame stride (32*32)

static __device__ __forceinline__ float bf2f(ushort_t u) {
    union { float f; unsigned int i; } x; x.i = ((unsigned int)u) << 16; return x.f;
}
static __device__ __forceinline__ ushort_t f2bf(float f) {
    union { float f; unsigned int i; } x; x.f = f;
    unsigned int u = x.i;
    unsigned int r = (u + 0x7FFFu + ((u >> 16) & 1u)) >> 16;
    return (ushort_t)r;
}

static __device__ __forceinline__ void gload16(const void* g, void* l) {
    __builtin_amdgcn_global_load_lds(
        (const __attribute__((address_space(1))) unsigned int*)g,
        (__attribute__((address_space(3))) unsigned int*)l, 16, 0, 0);
}

// raw barrier: no implicit vmcnt(0) drain
static __device__ __forceinline__ void wg_barrier() {
    asm volatile("" ::: "memory");
    __builtin_amdgcn_s_barrier();
    asm volatile("" ::: "memory");
}

// ---------------- K0: convert weights to bf16 ----------------
__global__ void k_cvt(const float* __restrict__ a, int n1,
                      const float* __restrict__ b, int n2,
                      ushort_t* __restrict__ o1, ushort_t* __restrict__ o2) {
    int i = blockIdx.x * blockDim.x + threadIdx.x;
    if (i < n1) o1[i] = f2bf(a[i]);
    if (i < n2) o2[i] = f2bf(b[i]);
}

// ---------------- K1: LayerNorm + transpose -> xn (65536 x 512) bf16 ----------------
__global__ __launch_bounds__(256) void k_ln_transpose(
        const float* __restrict__ x, const float* __restrict__ g,
        const float* __restrict__ bta, ushort_t* __restrict__ xn) {
    __shared__ float tile[32 * 513];
    __shared__ float gg[512];
    __shared__ float bb[512];
    int bid = blockIdx.x;
    int b = bid >> 9;
    int f = (bid >> 5) & 15;
    int h = bid & 31;
    int t = threadIdx.x;
    for (int c = t; c < 512; c += 256) { gg[c] = g[c]; bb[c] = bta[c]; }
    const float* xp = x + (size_t)b * SB + (size_t)f * SF + h * 32;
    int wq4 = (t & 7) * 4;
    int c0 = t >> 3;
    for (int it = 0; it < 16; ++it) {
        int c = c0 + it * 32;
        f32x4 v = *(const f32x4*)(xp + (size_t)c * SC + wq4);
        tile[(wq4 + 0) * 513 + c] = v[0];
        tile[(wq4 + 1) * 513 + c] = v[1];
        tile[(wq4 + 2) * 513 + c] = v[2];
        tile[(wq4 + 3) * 513 + c] = v[3];
    }
    __syncthreads();
    int lane = t & 63;
    int wave = t >> 6;
    for (int wi = 0; wi < 8; ++wi) {
        int ww = wave * 8 + wi;
        float s = 0.f, s2 = 0.f;
        #pragma unroll
        for (int j = 0; j < 8; ++j) {
            float v = tile[ww * 513 + lane + j * 64];
            s += v; s2 += v * v;
        }
        #pragma unroll
        for (int off = 32; off; off >>= 1) { s += __shfl_xor(s, off); s2 += __shfl_xor(s2, off); }
        float mean = s * (1.f / 512.f);
        float var = s2 * (1.f / 512.f) - mean * mean;
        float rstd = rsqrtf(var + 1e-5f);
        size_t row = ((size_t)((b * 32 + h) * 32 + ww)) * 16 + f;
        ushort_t* op = xn + row * 512 + lane * 8;
        union { ushort_t a[8]; s16x8 v; } u;
        #pragma unroll
        for (int j = 0; j < 8; ++j) {
            int c = lane * 8 + j;
            float v = tile[ww * 513 + c];
            u.a[j] = f2bf((v - mean) * rstd * gg[c] + bb[c]);
        }
        *(s16x8*)op = u.v;
    }
}

// ---------------- K2: fused QKV GEMM + attention ----------------
// block = 8 sequences (128 rows), 512 threads (8 waves). 4 passes of 2 heads:
// GEMM N=384 per pass, wave tile 64x96 (acc[4][6]) -> reads/MFMA 0.42.
// BK=64 dbuf staging (counted vmcnt(8)), 8-slot XOR swizzle. LDS 128 KB.
__global__ __launch_bounds__(512) void k_qkv_attn(
        const ushort_t* __restrict__ xn, const ushort_t* __restrict__ wq,
        const float* __restrict__ rb, ushort_t* __restrict__ att) {
    __shared__ __align__(16) char U[131072];
    // staging: A buf i @ i*16384 (16 KB each); B buf i @ 32768 + i*49152 (48 KB each)
    // attn (aliases staging, per head-half hh):
    //   qsm[hh] @ hh*16384            [128 m][64 d] swizzled
    //   ksm[hh] @ 32768 + hh*16384
    //   vT[hh]  @ 65536 + hh*17408    [64 d][136 m]
    //   ps      @ 100352  (8 waves x 256 ushort)
    //   ol      @ 104448  (8 waves x 1024 ushort)

    const int t = threadIdx.x;
    const int lane = t & 63;
    const int wv = t >> 6;
    const int l16 = lane & 15;
    const int lg = lane >> 4;
    const int m0 = blockIdx.x * 128;
    const int wm = wv >> 2;   // 0..1  (M half)
    const int wn = wv & 3;    // 0..3  (N quarter, 96 cols each)
    ushort_t* psw = (ushort_t*)(U + 100352) + wv * 256;
    ushort_t* olw = (ushort_t*)(U + 104448) + wv * 1024;

    // A K-slice: 128 rows x 64 K (1024 x 16B), 2 loads/thread
    auto stageA = [&](int buf, int kb) {
        ushort_t* dst = (ushort_t*)(U + buf * 16384);
        #pragma unroll
        for (int it = 0; it < 2; ++it) {
            int f = t + it * 512;
            int row = f >> 3, slot = f & 7;
            const ushort_t* src = xn + (size_t)(m0 + row) * 512 + kb * 64 + ((slot ^ (row & 7)) << 3);
            gload16(src, dst + f * 8);
        }
    };
    // B K-slice: 384 rows (seg*128 + hh*64 + d) x 64 K (3072 x 16B), 6 loads/thread
    auto stageB = [&](int buf, int kb, int hp) {
        ushort_t* dst = (ushort_t*)(U + 32768 + buf * 49152);
        #pragma unroll
        for (int it = 0; it < 6; ++it) {
            int f = t + it * 512;
            int brow = f >> 3, slot = f & 7;
            int seg = brow >> 7;
            int hh = (brow >> 6) & 1;
            int d = brow & 63;
            int wrow = seg * 512 + (hp * 2 + hh) * 64 + d;
            const ushort_t* src = wq + (size_t)wrow * 512 + kb * 64 + ((slot ^ (brow & 7)) << 3);
            gload16(src, dst + f * 8);
        }
    };

    for (int hp = 0; hp < 4; ++hp) {
        __syncthreads();                     // attn of previous pass done before re-alias
        stageA(0, 0); stageB(0, 0, hp);      // 8 loads in flight

        f32x4 acc[4][6];
        #pragma unroll
        for (int a1 = 0; a1 < 4; ++a1)
            #pragma unroll
            for (int a2 = 0; a2 < 6; ++a2)
                acc[a1][a2] = (f32x4){0.f, 0.f, 0.f, 0.f};

        for (int kb = 0; kb < 8; ++kb) {
            int cur = kb & 1;
            if (kb < 7) {
                stageA(cur ^ 1, kb + 1);
                stageB(cur ^ 1, kb + 1, hp);
                asm volatile("s_waitcnt vmcnt(8)" ::: "memory");   // stage(kb) landed
            } else {
                asm volatile("s_waitcnt vmcnt(0)" ::: "memory");
            }
            wg_barrier();
            const ushort_t* Ac = (const ushort_t*)(U + cur * 16384);
            const ushort_t* Bc = (const ushort_t*)(U + 32768 + cur * 49152);
            #pragma unroll
            for (int kk = 0; kk < 2; ++kk) {
                int koff = kk * 64 + lg * 16;   // byte offset within 128B row
                s16x8 af[4], bf[6];
                #pragma unroll
                for (int mf = 0; mf < 4; ++mf) {
                    int row = wm * 64 + mf * 16 + l16;
                    af[mf] = *(const s16x8*)&Ac[row * 64 + ((koff ^ ((row & 7) << 4)) >> 1)];
                }
                #pragma unroll
                for (int nf = 0; nf < 6; ++nf) {
                    int nrow = wn * 96 + nf * 16 + l16;
                    bf[nf] = *(const s16x8*)&Bc[nrow * 64 + ((koff ^ ((nrow & 7) << 4)) >> 1)];
                }
                #pragma unroll
                for (int mf = 0; mf < 4; ++mf)
                    #pragma unroll
                    for (int nf = 0; nf < 6; ++nf)
                        acc[mf][nf] = __builtin_amdgcn_mfma_f32_16x16x32_bf16(af[mf], bf[nf], acc[mf][nf], 0, 0, 0);
            }
            wg_barrier();                    // readers done before buffer reuse
        }

        // C-write: q/k swizzled [m][d] per head-half, V transposed [d][m]
        #pragma unroll
        for (int mf = 0; mf < 4; ++mf) {
            int mbase = wm * 64 + mf * 16 + lg * 4;
            #pragma unroll
            for (int nf = 0; nf < 6; ++nf) {
                int nn = wn * 96 + nf * 16 + l16;
                int seg = nn >> 7;
                int hh = (nn >> 6) & 1;
                int d = nn & 63;
                if (seg == 2) {
                    ushort_t* vTh = (ushort_t*)(U + 65536 + hh * 17408);
                    union { s16x4 v; ushort_t a[4]; } pk;
                    #pragma unroll
                    for (int r = 0; r < 4; ++r) pk.a[r] = f2bf(acc[mf][nf][r]);
                    *(s16x4*)&vTh[d * 136 + mbase] = pk.v;
                } else {
                    ushort_t* dst = (ushort_t*)(U + (seg ? 32768 : 0) + hh * 16384);
                    #pragma unroll
                    for (int r = 0; r < 4; ++r) {
                        int m = mbase + r;
                        dst[m * 64 + (d ^ ((m & 7) << 3))] = f2bf(acc[mf][nf][r]);
                    }
                }
            }
        }
        __syncthreads();

        // ---- attention: 16 (seq,head) pairs; wave wv = seq wv, pp = head half ----
        #pragma unroll
        for (int pp = 0; pp < 2; ++pp) {
            const ushort_t* qsmP = (const ushort_t*)(U + pp * 16384);
            const ushort_t* ksmP = (const ushort_t*)(U + 32768 + pp * 16384);
            const ushort_t* vTP  = (const ushort_t*)(U + 65536 + pp * 17408);
            int hd = hp * 2 + pp;
            int arow = wv * 16 + l16;
            int sw = (arow & 7) << 4;
            f32x4 sacc = (f32x4){0.f, 0.f, 0.f, 0.f};
            #pragma unroll
            for (int kk = 0; kk < 2; ++kk) {
                int off = kk * 64 + lg * 16;
                s16x8 ka = *(const s16x8*)&ksmP[arow * 64 + ((off ^ sw) >> 1)];
                s16x8 qb = *(const s16x8*)&qsmP[arow * 64 + ((off ^ sw) >> 1)];
                sacc = __builtin_amdgcn_mfma_f32_16x16x32_bf16(ka, qb, sacc, 0, 0, 0);
            }
            // lane holds S[j][i]: i = l16, j = lg*4+r
            const float* rbp = rb + l16 * 64 + lg * 4;
            float p[4];
            float mx = -1e30f;
            #pragma unroll
            for (int r = 0; r < 4; ++r) {
                p[r] = sacc[r] * 0.125f + rbp[r];
                mx = fmaxf(mx, p[r]);
            }
            mx = fmaxf(mx, __shfl_xor(mx, 16));
            mx = fmaxf(mx, __shfl_xor(mx, 32));
            float sum = 0.f;
            #pragma unroll
            for (int r = 0; r < 4; ++r) { p[r] = __expf(p[r] - mx); sum += p[r]; }
            sum += __shfl_xor(sum, 16);
            sum += __shfl_xor(sum, 32);
            float inv = 1.f / sum;
            {
                union { s16x4 v; ushort_t a[4]; } pk;
                #pragma unroll
                for (int r = 0; r < 4; ++r) pk.a[r] = f2bf(p[r] * inv);
                *(s16x4*)&psw[l16 * 16 + lg * 4] = pk.v;   // P[i][j]
            }
            asm volatile("s_waitcnt lgkmcnt(0)" ::: "memory");
            // PV: A = P rows i (j padded to 32 with zeros), B = vT rows d
            s16x8 ap = (s16x8){0, 0, 0, 0, 0, 0, 0, 0};
            if (lg < 2) ap = *(const s16x8*)&psw[l16 * 16 + lg * 8];
            int jj = (lg < 2) ? lg * 8 : 0;
            f32x4 ov[4];
            #pragma unroll
            for (int ff = 0; ff < 4; ++ff) {
                int d = ff * 16 + l16;
                s16x8 bv = *(const s16x8*)&vTP[d * 136 + wv * 16 + jj];
                ov[ff] = __builtin_amdgcn_mfma_f32_16x16x32_bf16(ap, bv, (f32x4){0.f, 0.f, 0.f, 0.f}, 0, 0, 0);
            }
            // stage output through this wave's private LDS rows for 16B stores
            #pragma unroll
            for (int ff = 0; ff < 4; ++ff)
                #pragma unroll
                for (int r = 0; r < 4; ++r)
                    olw[(lg * 4 + r) * 64 + ff * 16 + l16] = f2bf(ov[ff][r]);
            asm volatile("s_waitcnt lgkmcnt(0)" ::: "memory");
            {
                int i2 = lane >> 2;
                int c2 = (lane & 3) * 16;
                s16x8 w0 = *(const s16x8*)&olw[i2 * 64 + c2];
                s16x8 w1 = *(const s16x8*)&olw[i2 * 64 + c2 + 8];
                ushort_t* op = att + (size_t)(m0 + wv * 16 + i2) * 512 + hd * 64 + c2;
                *(s16x8*)op = w0;
                *(s16x8*)(op + 8) = w1;
            }
        }
    }
}

// ---------------- K3: proj GEMM + bias + residual + transpose-out ----------------
// block = (b, h, f-quad, n-half): M=128 rows, N=256, K=512. 512 threads.
// BK=32, 3-deep ring + counted vmcnt. LDS 72 KB.
__global__ __launch_bounds__(512) void k_proj_out(
        const ushort_t* __restrict__ att, const ushort_t* __restrict__ wp,
        const float* __restrict__ bp, const float* __restrict__ x,
        float* __restrict__ out) {
    __shared__ __align__(16) char U[73728];   // A: 3x8192 @0, B: 3x16384 @24576
    int bid = blockIdx.x;
    int nh = bid & 1;
    int fq = (bid >> 1) & 3;
    int h = (bid >> 3) & 31;
    int b = bid >> 8;
    const int n0 = nh * 256;
    const int t = threadIdx.x;
    const int lane = t & 63;
    const int wv = t >> 6;
    const int l16 = lane & 15;
    const int lg = lane >> 4;
    const int wm = wv >> 2;   // 0..1
    const int wn = wv & 3;    // 0..3
    size_t attbase = ((size_t)(b * 32 + h) * 32) * 16 + fq * 4;  // + w*16 + fl

    auto stA = [&](int buf, int ks) {
        int row = t >> 2, slot = t & 3;
        int w = row & 31, fl = row >> 5;
        const ushort_t* src = att + (attbase + (size_t)w * 16 + fl) * 512 + ks * 32 + ((slot ^ ((row >> 2) & 3)) << 3);
        gload16(src, (ushort_t*)(U + buf * 8192) + t * 8);
    };
    auto stB = [&](int buf, int ks) {
        #pragma unroll
        for (int i = 0; i < 2; ++i) {
            int u = t + i * 512;      // 1024 units (256 rows x 4 slots)
            int row = u >> 2, slot = u & 3;
            const ushort_t* src = wp + (size_t)(n0 + row) * 512 + ks * 32 + ((slot ^ ((row >> 2) & 3)) << 3);
            gload16(src, (ushort_t*)(U + 24576 + buf * 16384) + u * 8);
        }
    };

    f32x4 acc[4][4];
    #pragma unroll
    for (int m = 0; m < 4; ++m)
        #pragma unroll
        for (int n = 0; n < 4; ++n)
            acc[m][n] = (f32x4){0.f, 0.f, 0.f, 0.f};

    stA(0, 0); stB(0, 0);    // 3 loads
    stA(1, 1); stB(1, 1);    // 3 loads -> 6 in flight
    for (int ks = 0; ks < 16; ++ks) {
        int cur = ks % 3;
        if (ks < 14) {
            stA((ks + 2) % 3, ks + 2);
            stB((ks + 2) % 3, ks + 2);
            asm volatile("s_waitcnt vmcnt(6)" ::: "memory");
        } else if (ks == 14) {
            asm volatile("s_waitcnt vmcnt(3)" ::: "memory");
        } else {
            asm volatile("s_waitcnt vmcnt(0)" ::: "memory");
        }
        wg_barrier();
        s16x8 af[4], bf[4];
        #pragma unroll
        for (int mf = 0; mf < 4; ++mf) {
            int row = wm * 64 + mf * 16 + l16;
            af[mf] = *(const s16x8*)((ushort_t*)(U + cur * 8192) + row * 32 + ((lg ^ ((row >> 2) & 3)) << 3));
        }
        #pragma unroll
        for (int nf = 0; nf < 4; ++nf) {
            int nrow = wn * 64 + nf * 16 + l16;
            bf[nf] = *(const s16x8*)((ushort_t*)(U + 24576 + cur * 16384) + nrow * 32 + ((lg ^ ((nrow >> 2) & 3)) << 3));
        }
        #pragma unroll
        for (int mf = 0; mf < 4; ++mf)
            #pragma unroll
            for (int nf = 0; nf < 4; ++nf)
                acc[mf][nf] = __builtin_amdgcn_mfma_f32_16x16x32_bf16(bf[nf], af[mf], acc[mf][nf], 0, 0, 0);
        wg_barrier();
    }

    // epilogue: direct stores, bias + residual fused (D: col l16 = M, row lg*4+r = N)
    size_t obase = (size_t)b * SB + (size_t)(fq * 4) * SF + h * 32;
    #pragma unroll
    for (int mf = 0; mf < 4; ++mf) {
        int m = wm * 64 + mf * 16 + l16;
        int w = m & 31, fl = m >> 5;
        size_t base_m = obase + (size_t)fl * SF + w;
        #pragma unroll
        for (int nf = 0; nf < 4; ++nf) {
            int col0 = n0 + wn * 64 + nf * 16 + lg * 4;
            #pragma unroll
            for (int r = 0; r < 4; ++r) {
                int col = col0 + r;
                size_t a = base_m + (size_t)col * SC;
                out[a] = acc[mf][nf][r] + bp[col] + x[a];
            }
        }
    }
}

extern "C" void kernel_launch(void* const* d_in, const int* in_sizes, int n_in,
                              void* d_out, int out_size, void* d_ws, size_t ws_size,
                              hipStream_t stream) {
    const float* x     = (const float*)d_in[0];
    const float* wqkv  = (const float*)d_in[1];
    const float* wproj = (const float*)d_in[2];
    const float* bproj = (const float*)d_in[3];
    const float* rb    = (const float*)d_in[4];
    const float* lng   = (const float*)d_in[5];
    const float* lnb   = (const float*)d_in[6];
    float* out = (float*)d_out;
    char* ws = (char*)d_ws;
    ushort_t* xn   = (ushort_t*)(ws);                  // 64 MB
    ushort_t* att  = (ushort_t*)(ws + 67108864);       // 64 MB
    ushort_t* wq16 = (ushort_t*)(ws + 134217728);      // 1.5 MB
    ushort_t* wp16 = (ushort_t*)(ws + 135790592);      // 0.5 MB

    k_cvt<<<3072, 256, 0, stream>>>(wqkv, 1536 * 512, wproj, 512 * 512, wq16, wp16);
    k_ln_transpose<<<2048, 256, 0, stream>>>(x, lng, lnb, xn);
    k_qkv_attn<<<512, 512, 0, stream>>>(xn, wq16, rb, att);
    k_proj_out<<<1024, 512, 0, stream>>>(att, wp16, bproj, x, out);
}

// Round 9
// 488.487 us; speedup vs baseline: 1.0034x; 1.0034x over previous
//
#include <hip/hip_runtime.h>

typedef unsigned short ushort_t;
typedef __attribute__((ext_vector_type(4))) float f32x4;
typedef __attribute__((ext_vector_type(8))) short s16x8;
typedef __attribute__((ext_vector_type(4))) short s16x4;

#define SB 8388608   // x batch stride (512*16*32*32)
#define SC 16384     // x channel stride (16*32*32)
#define SF 1024      // x frame stride (32*32)

static __device__ __forceinline__ float bf2f(ushort_t u) {
    union { float f; unsigned int i; } x; x.i = ((unsigned int)u) << 16; return x.f;
}
static __device__ __forceinline__ ushort_t f2bf(float f) {
    union { float f; unsigned int i; } x; x.f = f;
    unsigned int u = x.i;
    unsigned int r = (u + 0x7FFFu + ((u >> 16) & 1u)) >> 16;
    return (ushort_t)r;
}

static __device__ __forceinline__ void gload16(const void* g, void* l) {
    __builtin_amdgcn_global_load_lds(
        (const __attribute__((address_space(1))) unsigned int*)g,
        (__attribute__((address_space(3))) unsigned int*)l, 16, 0, 0);
}

// raw barrier: no implicit vmcnt(0) drain
static __device__ __forceinline__ void wg_barrier() {
    asm volatile("" ::: "memory");
    __builtin_amdgcn_s_barrier();
    asm volatile("" ::: "memory");
}

// ---------------- K0: convert weights to bf16 ----------------
__global__ void k_cvt(const float* __restrict__ a, int n1,
                      const float* __restrict__ b, int n2,
                      ushort_t* __restrict__ o1, ushort_t* __restrict__ o2) {
    int i = blockIdx.x * blockDim.x + threadIdx.x;
    if (i < n1) o1[i] = f2bf(a[i]);
    if (i < n2) o2[i] = f2bf(b[i]);
}

// ---------------- K1: LayerNorm + transpose -> xn (65536 x 512) bf16 ----------------
__global__ __launch_bounds__(256) void k_ln_transpose(
        const float* __restrict__ x, const float* __restrict__ g,
        const float* __restrict__ bta, ushort_t* __restrict__ xn) {
    __shared__ float tile[32 * 513];
    __shared__ float gg[512];
    __shared__ float bb[512];
    int bid = blockIdx.x;
    int b = bid >> 9;
    int f = (bid >> 5) & 15;
    int h = bid & 31;
    int t = threadIdx.x;
    for (int c = t; c < 512; c += 256) { gg[c] = g[c]; bb[c] = bta[c]; }
    const float* xp = x + (size_t)b * SB + (size_t)f * SF + h * 32;
    int wq4 = (t & 7) * 4;
    int c0 = t >> 3;
    for (int it = 0; it < 16; ++it) {
        int c = c0 + it * 32;
        f32x4 v = *(const f32x4*)(xp + (size_t)c * SC + wq4);
        tile[(wq4 + 0) * 513 + c] = v[0];
        tile[(wq4 + 1) * 513 + c] = v[1];
        tile[(wq4 + 2) * 513 + c] = v[2];
        tile[(wq4 + 3) * 513 + c] = v[3];
    }
    __syncthreads();
    int lane = t & 63;
    int wave = t >> 6;
    for (int wi = 0; wi < 8; ++wi) {
        int ww = wave * 8 + wi;
        float s = 0.f, s2 = 0.f;
        #pragma unroll
        for (int j = 0; j < 8; ++j) {
            float v = tile[ww * 513 + lane + j * 64];
            s += v; s2 += v * v;
        }
        #pragma unroll
        for (int off = 32; off; off >>= 1) { s += __shfl_xor(s, off); s2 += __shfl_xor(s2, off); }
        float mean = s * (1.f / 512.f);
        float var = s2 * (1.f / 512.f) - mean * mean;
        float rstd = rsqrtf(var + 1e-5f);
        size_t row = ((size_t)((b * 32 + h) * 32 + ww)) * 16 + f;
        ushort_t* op = xn + row * 512 + lane * 8;
        union { ushort_t a[8]; s16x8 v; } u;
        #pragma unroll
        for (int j = 0; j < 8; ++j) {
            int c = lane * 8 + j;
            float v = tile[ww * 513 + c];
            u.a[j] = f2bf((v - mean) * rstd * gg[c] + bb[c]);
        }
        *(s16x8*)op = u.v;
    }
}

// ---------------- K2: fused QKV GEMM + attention ----------------
// block = 8 sequences (128 rows), 512 threads (8 waves). 4 passes of 2 heads:
// GEMM N=384 per pass, wave tile 64x96 (acc[4][6]) -> reads/MFMA 0.42.
// __launch_bounds__(512,2): VGPR cap 256 -> acc stays in registers (r8 spilled
// at the 128 cap). BK=64 dbuf staging (counted vmcnt(8)). LDS 128 KB.
__global__ __launch_bounds__(512, 2) void k_qkv_attn(
        const ushort_t* __restrict__ xn, const ushort_t* __restrict__ wq,
        const float* __restrict__ rb, ushort_t* __restrict__ att) {
    __shared__ __align__(16) char U[131072];
    // staging: A buf i @ i*16384 (16 KB each); B buf i @ 32768 + i*49152 (48 KB each)
    // attn (aliases staging, per head-half hh):
    //   qsm[hh] @ hh*16384            [128 m][64 d] swizzled
    //   ksm[hh] @ 32768 + hh*16384
    //   vT[hh]  @ 65536 + hh*17408    [64 d][136 m]
    //   ps      @ 100352  (8 waves x 256 ushort)
    //   ol      @ 104448  (8 waves x 1024 ushort)

    const int t = threadIdx.x;
    const int lane = t & 63;
    const int wv = t >> 6;
    const int l16 = lane & 15;
    const int lg = lane >> 4;
    const int m0 = blockIdx.x * 128;
    const int wm = wv >> 2;   // 0..1  (M half)
    const int wn = wv & 3;    // 0..3  (N quarter, 96 cols each)
    ushort_t* psw = (ushort_t*)(U + 100352) + wv * 256;
    ushort_t* olw = (ushort_t*)(U + 104448) + wv * 1024;

    // A K-slice: 128 rows x 64 K (1024 x 16B), 2 loads/thread
    auto stageA = [&](int buf, int kb) {
        ushort_t* dst = (ushort_t*)(U + buf * 16384);
        #pragma unroll
        for (int it = 0; it < 2; ++it) {
            int f = t + it * 512;
            int row = f >> 3, slot = f & 7;
            const ushort_t* src = xn + (size_t)(m0 + row) * 512 + kb * 64 + ((slot ^ (row & 7)) << 3);
            gload16(src, dst + f * 8);
        }
    };
    // B K-slice: 384 rows (seg*128 + hh*64 + d) x 64 K (3072 x 16B), 6 loads/thread
    auto stageB = [&](int buf, int kb, int hp) {
        ushort_t* dst = (ushort_t*)(U + 32768 + buf * 49152);
        #pragma unroll
        for (int it = 0; it < 6; ++it) {
            int f = t + it * 512;
            int brow = f >> 3, slot = f & 7;
            int seg = brow >> 7;
            int hh = (brow >> 6) & 1;
            int d = brow & 63;
            int wrow = seg * 512 + (hp * 2 + hh) * 64 + d;
            const ushort_t* src = wq + (size_t)wrow * 512 + kb * 64 + ((slot ^ (brow & 7)) << 3);
            gload16(src, dst + f * 8);
        }
    };

    for (int hp = 0; hp < 4; ++hp) {
        __syncthreads();                     // attn of previous pass done before re-alias
        stageA(0, 0); stageB(0, 0, hp);      // 8 loads in flight

        f32x4 acc[4][6];
        #pragma unroll
        for (int a1 = 0; a1 < 4; ++a1)
            #pragma unroll
            for (int a2 = 0; a2 < 6; ++a2)
                acc[a1][a2] = (f32x4){0.f, 0.f, 0.f, 0.f};

        for (int kb = 0; kb < 8; ++kb) {
            int cur = kb & 1;
            if (kb < 7) {
                stageA(cur ^ 1, kb + 1);
                stageB(cur ^ 1, kb + 1, hp);
                asm volatile("s_waitcnt vmcnt(8)" ::: "memory");   // stage(kb) landed
            } else {
                asm volatile("s_waitcnt vmcnt(0)" ::: "memory");
            }
            wg_barrier();
            const ushort_t* Ac = (const ushort_t*)(U + cur * 16384);
            const ushort_t* Bc = (const ushort_t*)(U + 32768 + cur * 49152);
            #pragma unroll
            for (int kk = 0; kk < 2; ++kk) {
                int koff = kk * 64 + lg * 16;   // byte offset within 128B row
                s16x8 af[4], bf[6];
                #pragma unroll
                for (int mf = 0; mf < 4; ++mf) {
                    int row = wm * 64 + mf * 16 + l16;
                    af[mf] = *(const s16x8*)&Ac[row * 64 + ((koff ^ ((row & 7) << 4)) >> 1)];
                }
                #pragma unroll
                for (int nf = 0; nf < 6; ++nf) {
                    int nrow = wn * 96 + nf * 16 + l16;
                    bf[nf] = *(const s16x8*)&Bc[nrow * 64 + ((koff ^ ((nrow & 7) << 4)) >> 1)];
                }
                #pragma unroll
                for (int mf = 0; mf < 4; ++mf)
                    #pragma unroll
                    for (int nf = 0; nf < 6; ++nf)
                        acc[mf][nf] = __builtin_amdgcn_mfma_f32_16x16x32_bf16(af[mf], bf[nf], acc[mf][nf], 0, 0, 0);
            }
            wg_barrier();                    // readers done before buffer reuse
        }

        // C-write: q/k swizzled [m][d] per head-half, V transposed [d][m]
        #pragma unroll
        for (int mf = 0; mf < 4; ++mf) {
            int mbase = wm * 64 + mf * 16 + lg * 4;
            #pragma unroll
            for (int nf = 0; nf < 6; ++nf) {
                int nn = wn * 96 + nf * 16 + l16;
                int seg = nn >> 7;
                int hh = (nn >> 6) & 1;
                int d = nn & 63;
                if (seg == 2) {
                    ushort_t* vTh = (ushort_t*)(U + 65536 + hh * 17408);
                    union { s16x4 v; ushort_t a[4]; } pk;
                    #pragma unroll
                    for (int r = 0; r < 4; ++r) pk.a[r] = f2bf(acc[mf][nf][r]);
                    *(s16x4*)&vTh[d * 136 + mbase] = pk.v;
                } else {
                    ushort_t* dst = (ushort_t*)(U + (seg ? 32768 : 0) + hh * 16384);
                    #pragma unroll
                    for (int r = 0; r < 4; ++r) {
                        int m = mbase + r;
                        dst[m * 64 + (d ^ ((m & 7) << 3))] = f2bf(acc[mf][nf][r]);
                    }
                }
            }
        }
        __syncthreads();

        // ---- attention: 16 (seq,head) pairs; wave wv = seq wv, pp = head half ----
        #pragma unroll
        for (int pp = 0; pp < 2; ++pp) {
            const ushort_t* qsmP = (const ushort_t*)(U + pp * 16384);
            const ushort_t* ksmP = (const ushort_t*)(U + 32768 + pp * 16384);
            const ushort_t* vTP  = (const ushort_t*)(U + 65536 + pp * 17408);
            int hd = hp * 2 + pp;
            int arow = wv * 16 + l16;
            int sw = (arow & 7) << 4;
            f32x4 sacc = (f32x4){0.f, 0.f, 0.f, 0.f};
            #pragma unroll
            for (int kk = 0; kk < 2; ++kk) {
                int off = kk * 64 + lg * 16;
                s16x8 ka = *(const s16x8*)&ksmP[arow * 64 + ((off ^ sw) >> 1)];
                s16x8 qb = *(const s16x8*)&qsmP[arow * 64 + ((off ^ sw) >> 1)];
                sacc = __builtin_amdgcn_mfma_f32_16x16x32_bf16(ka, qb, sacc, 0, 0, 0);
            }
            // lane holds S[j][i]: i = l16, j = lg*4+r
            const float* rbp = rb + l16 * 64 + lg * 4;
            float p[4];
            float mx = -1e30f;
            #pragma unroll
            for (int r = 0; r < 4; ++r) {
                p[r] = sacc[r] * 0.125f + rbp[r];
                mx = fmaxf(mx, p[r]);
            }
            mx = fmaxf(mx, __shfl_xor(mx, 16));
            mx = fmaxf(mx, __shfl_xor(mx, 32));
            float sum = 0.f;
            #pragma unroll
            for (int r = 0; r < 4; ++r) { p[r] = __expf(p[r] - mx); sum += p[r]; }
            sum += __shfl_xor(sum, 16);
            sum += __shfl_xor(sum, 32);
            float inv = 1.f / sum;
            {
                union { s16x4 v; ushort_t a[4]; } pk;
                #pragma unroll
                for (int r = 0; r < 4; ++r) pk.a[r] = f2bf(p[r] * inv);
                *(s16x4*)&psw[l16 * 16 + lg * 4] = pk.v;   // P[i][j]
            }
            asm volatile("s_waitcnt lgkmcnt(0)" ::: "memory");
            // PV: A = P rows i (j padded to 32 with zeros), B = vT rows d
            s16x8 ap = (s16x8){0, 0, 0, 0, 0, 0, 0, 0};
            if (lg < 2) ap = *(const s16x8*)&psw[l16 * 16 + lg * 8];
            int jj = (lg < 2) ? lg * 8 : 0;
            f32x4 ov[4];
            #pragma unroll
            for (int ff = 0; ff < 4; ++ff) {
                int d = ff * 16 + l16;
                s16x8 bv = *(const s16x8*)&vTP[d * 136 + wv * 16 + jj];
                ov[ff] = __builtin_amdgcn_mfma_f32_16x16x32_bf16(ap, bv, (f32x4){0.f, 0.f, 0.f, 0.f}, 0, 0, 0);
            }
            // stage output through this wave's private LDS rows for 16B stores
            #pragma unroll
            for (int ff = 0; ff < 4; ++ff)
                #pragma unroll
                for (int r = 0; r < 4; ++r)
                    olw[(lg * 4 + r) * 64 + ff * 16 + l16] = f2bf(ov[ff][r]);
            asm volatile("s_waitcnt lgkmcnt(0)" ::: "memory");
            {
                int i2 = lane >> 2;
                int c2 = (lane & 3) * 16;
                s16x8 w0 = *(const s16x8*)&olw[i2 * 64 + c2];
                s16x8 w1 = *(const s16x8*)&olw[i2 * 64 + c2 + 8];
                ushort_t* op = att + (size_t)(m0 + wv * 16 + i2) * 512 + hd * 64 + c2;
                *(s16x8*)op = w0;
                *(s16x8*)(op + 8) = w1;
            }
        }
    }
}

// ---------------- K3: proj GEMM + bias + residual + transpose-out ----------------
// block = (b, h, f-quad, n-half): M=128 rows, N=256, K=512. 512 threads.
// BK=32, 3-deep ring + counted vmcnt. LDS 72 KB. launch_bounds(512,2) -> no spill.
__global__ __launch_bounds__(512, 2) void k_proj_out(
        const ushort_t* __restrict__ att, const ushort_t* __restrict__ wp,
        const float* __restrict__ bp, const float* __restrict__ x,
        float* __restrict__ out) {
    __shared__ __align__(16) char U[73728];   // A: 3x8192 @0, B: 3x16384 @24576
    int bid = blockIdx.x;
    int nh = bid & 1;
    int fq = (bid >> 1) & 3;
    int h = (bid >> 3) & 31;
    int b = bid >> 8;
    const int n0 = nh * 256;
    const int t = threadIdx.x;
    const int lane = t & 63;
    const int wv = t >> 6;
    const int l16 = lane & 15;
    const int lg = lane >> 4;
    const int wm = wv >> 2;   // 0..1
    const int wn = wv & 3;    // 0..3
    size_t attbase = ((size_t)(b * 32 + h) * 32) * 16 + fq * 4;  // + w*16 + fl

    auto stA = [&](int buf, int ks) {
        int row = t >> 2, slot = t & 3;
        int w = row & 31, fl = row >> 5;
        const ushort_t* src = att + (attbase + (size_t)w * 16 + fl) * 512 + ks * 32 + ((slot ^ ((row >> 2) & 3)) << 3);
        gload16(src, (ushort_t*)(U + buf * 8192) + t * 8);
    };
    auto stB = [&](int buf, int ks) {
        #pragma unroll
        for (int i = 0; i < 2; ++i) {
            int u = t + i * 512;      // 1024 units (256 rows x 4 slots)
            int row = u >> 2, slot = u & 3;
            const ushort_t* src = wp + (size_t)(n0 + row) * 512 + ks * 32 + ((slot ^ ((row >> 2) & 3)) << 3);
            gload16(src, (ushort_t*)(U + 24576 + buf * 16384) + u * 8);
        }
    };

    f32x4 acc[4][4];
    #pragma unroll
    for (int m = 0; m < 4; ++m)
        #pragma unroll
        for (int n = 0; n < 4; ++n)
            acc[m][n] = (f32x4){0.f, 0.f, 0.f, 0.f};

    stA(0, 0); stB(0, 0);    // 3 loads
    stA(1, 1); stB(1, 1);    // 3 loads -> 6 in flight
    for (int ks = 0; ks < 16; ++ks) {
        int cur = ks % 3;
        if (ks < 14) {
            stA((ks + 2) % 3, ks + 2);
            stB((ks + 2) % 3, ks + 2);
            asm volatile("s_waitcnt vmcnt(6)" ::: "memory");
        } else if (ks == 14) {
            asm volatile("s_waitcnt vmcnt(3)" ::: "memory");
        } else {
            asm volatile("s_waitcnt vmcnt(0)" ::: "memory");
        }
        wg_barrier();
        s16x8 af[4], bf[4];
        #pragma unroll
        for (int mf = 0; mf < 4; ++mf) {
            int row = wm * 64 + mf * 16 + l16;
            af[mf] = *(const s16x8*)((ushort_t*)(U + cur * 8192) + row * 32 + ((lg ^ ((row >> 2) & 3)) << 3));
        }
        #pragma unroll
        for (int nf = 0; nf < 4; ++nf) {
            int nrow = wn * 64 + nf * 16 + l16;
            bf[nf] = *(const s16x8*)((ushort_t*)(U + 24576 + cur * 16384) + nrow * 32 + ((lg ^ ((nrow >> 2) & 3)) << 3));
        }
        #pragma unroll
        for (int mf = 0; mf < 4; ++mf)
            #pragma unroll
            for (int nf = 0; nf < 4; ++nf)
                acc[mf][nf] = __builtin_amdgcn_mfma_f32_16x16x32_bf16(bf[nf], af[mf], acc[mf][nf], 0, 0, 0);
        wg_barrier();
    }

    // epilogue: direct stores, bias + residual fused (D: col l16 = M, row lg*4+r = N)
    size_t obase = (size_t)b * SB + (size_t)(fq * 4) * SF + h * 32;
    #pragma unroll
    for (int mf = 0; mf < 4; ++mf) {
        int m = wm * 64 + mf * 16 + l16;
        int w = m & 31, fl = m >> 5;
        size_t base_m = obase + (size_t)fl * SF + w;
        #pragma unroll
        for (int nf = 0; nf < 4; ++nf) {
            int col0 = n0 + wn * 64 + nf * 16 + lg * 4;
            #pragma unroll
            for (int r = 0; r < 4; ++r) {
                int col = col0 + r;
                size_t a = base_m + (size_t)col * SC;
                out[a] = acc[mf][nf][r] + bp[col] + x[a];
            }
        }
    }
}

extern "C" void kernel_launch(void* const* d_in, const int* in_sizes, int n_in,
                              void* d_out, int out_size, void* d_ws, size_t ws_size,
                              hipStream_t stream) {
    const float* x     = (const float*)d_in[0];
    const float* wqkv  = (const float*)d_in[1];
    const float* wproj = (const float*)d_in[2];
    const float* bproj = (const float*)d_in[3];
    const float* rb    = (const float*)d_in[4];
    const float* lng   = (const float*)d_in[5];
    const float* lnb   = (const float*)d_in[6];
    float* out = (float*)d_out;
    char* ws = (char*)d_ws;
    ushort_t* xn   = (ushort_t*)(ws);                  // 64 MB
    ushort_t* att  = (ushort_t*)(ws + 67108864);       // 64 MB
    ushort_t* wq16 = (ushort_t*)(ws + 134217728);      // 1.5 MB
    ushort_t* wp16 = (ushort_t*)(ws + 135790592);      // 0.5 MB

    k_cvt<<<3072, 256, 0, stream>>>(wqkv, 1536 * 512, wproj, 512 * 512, wq16, wp16);
    k_ln_transpose<<<2048, 256, 0, stream>>>(x, lng, lnb, xn);
    k_qkv_attn<<<512, 512, 0, stream>>>(xn, wq16, rb, att);
    k_proj_out<<<1024, 512, 0, stream>>>(att, wp16, bproj, x, out);
}

// Round 10
// 458.953 us; speedup vs baseline: 1.0679x; 1.0644x over previous
//
#include <hip/hip_runtime.h>

typedef unsigned short ushort_t;
typedef __attribute__((ext_vector_type(4))) float f32x4;
typedef __attribute__((ext_vector_type(8))) short s16x8;
typedef __attribute__((ext_vector_type(4))) short s16x4;

#define SB 8388608   // x batch stride (512*16*32*32)
#define SC 16384     // x channel stride (16*32*32)
#define SF 1024      // x frame stride (32*32)

static __device__ __forceinline__ float bf2f(ushort_t u) {
    union { float f; unsigned int i; } x; x.i = ((unsigned int)u) << 16; return x.f;
}
static __device__ __forceinline__ ushort_t f2bf(float f) {
    union { float f; unsigned int i; } x; x.f = f;
    unsigned int u = x.i;
    unsigned int r = (u + 0x7FFFu + ((u >> 16) & 1u)) >> 16;
    return (ushort_t)r;
}

static __device__ __forceinline__ void gload16(const void* g, void* l) {
    __builtin_amdgcn_global_load_lds(
        (const __attribute__((address_space(1))) unsigned int*)g,
        (__attribute__((address_space(3))) unsigned int*)l, 16, 0, 0);
}

// raw barrier: no implicit vmcnt(0) drain
static __device__ __forceinline__ void wg_barrier() {
    asm volatile("" ::: "memory");
    __builtin_amdgcn_s_barrier();
    asm volatile("" ::: "memory");
}

// ---------------- K0: convert weights to bf16 ----------------
__global__ void k_cvt(const float* __restrict__ a, int n1,
                      const float* __restrict__ b, int n2,
                      ushort_t* __restrict__ o1, ushort_t* __restrict__ o2) {
    int i = blockIdx.x * blockDim.x + threadIdx.x;
    if (i < n1) o1[i] = f2bf(a[i]);
    if (i < n2) o2[i] = f2bf(b[i]);
}

// ---------------- K1: LayerNorm + transpose -> xn (65536 x 512) bf16 ----------------
__global__ __launch_bounds__(256) void k_ln_transpose(
        const float* __restrict__ x, const float* __restrict__ g,
        const float* __restrict__ bta, ushort_t* __restrict__ xn) {
    __shared__ float tile[32 * 513];
    __shared__ float gg[512];
    __shared__ float bb[512];
    int bid = blockIdx.x;
    int b = bid >> 9;
    int f = (bid >> 5) & 15;
    int h = bid & 31;
    int t = threadIdx.x;
    for (int c = t; c < 512; c += 256) { gg[c] = g[c]; bb[c] = bta[c]; }
    const float* xp = x + (size_t)b * SB + (size_t)f * SF + h * 32;
    int wq4 = (t & 7) * 4;
    int c0 = t >> 3;
    for (int it = 0; it < 16; ++it) {
        int c = c0 + it * 32;
        f32x4 v = *(const f32x4*)(xp + (size_t)c * SC + wq4);
        tile[(wq4 + 0) * 513 + c] = v[0];
        tile[(wq4 + 1) * 513 + c] = v[1];
        tile[(wq4 + 2) * 513 + c] = v[2];
        tile[(wq4 + 3) * 513 + c] = v[3];
    }
    __syncthreads();
    int lane = t & 63;
    int wave = t >> 6;
    for (int wi = 0; wi < 8; ++wi) {
        int ww = wave * 8 + wi;
        float s = 0.f, s2 = 0.f;
        #pragma unroll
        for (int j = 0; j < 8; ++j) {
            float v = tile[ww * 513 + lane + j * 64];
            s += v; s2 += v * v;
        }
        #pragma unroll
        for (int off = 32; off; off >>= 1) { s += __shfl_xor(s, off); s2 += __shfl_xor(s2, off); }
        float mean = s * (1.f / 512.f);
        float var = s2 * (1.f / 512.f) - mean * mean;
        float rstd = rsqrtf(var + 1e-5f);
        size_t row = ((size_t)((b * 32 + h) * 32 + ww)) * 16 + f;
        ushort_t* op = xn + row * 512 + lane * 8;
        union { ushort_t a[8]; s16x8 v; } u;
        #pragma unroll
        for (int j = 0; j < 8; ++j) {
            int c = lane * 8 + j;
            float v = tile[ww * 513 + c];
            u.a[j] = f2bf((v - mean) * rstd * gg[c] + bb[c]);
        }
        *(s16x8*)op = u.v;
    }
}

// ---------------- K2: fused QKV GEMM + attention ----------------
// block = 8 sequences (128 rows), 512 threads (8 waves). 4 passes of 2 heads:
// GEMM N=384 per pass, wave tile 64x96 (acc[4][6]). Inner loop split into
// two nf-halves (af[4]+bf[3] live = 28 frag VGPRs) to fit the 128 arch-VGPR
// budget without scratch spill (r8/r9 spilled with bf[6]).
__global__ __launch_bounds__(512, 2) void k_qkv_attn(
        const ushort_t* __restrict__ xn, const ushort_t* __restrict__ wq,
        const float* __restrict__ rb, ushort_t* __restrict__ att) {
    __shared__ __align__(16) char U[131072];
    // staging: A buf i @ i*16384 (16 KB each); B buf i @ 32768 + i*49152 (48 KB each)
    // attn (aliases staging, per head-half hh):
    //   qsm[hh] @ hh*16384; ksm[hh] @ 32768 + hh*16384; vT[hh] @ 65536 + hh*17408
    //   ps @ 100352 (8x256 ushort); ol @ 104448 (8x1024 ushort)

    const int t = threadIdx.x;
    const int lane = t & 63;
    const int wv = t >> 6;
    const int l16 = lane & 15;
    const int lg = lane >> 4;
    const int m0 = blockIdx.x * 128;
    const int wm = wv >> 2;   // 0..1  (M half)
    const int wn = wv & 3;    // 0..3  (N quarter, 96 cols each)
    ushort_t* psw = (ushort_t*)(U + 100352) + wv * 256;
    ushort_t* olw = (ushort_t*)(U + 104448) + wv * 1024;

    // A K-slice: 128 rows x 64 K (1024 x 16B), 2 loads/thread
    auto stageA = [&](int buf, int kb) {
        ushort_t* dst = (ushort_t*)(U + buf * 16384);
        #pragma unroll
        for (int it = 0; it < 2; ++it) {
            int f = t + it * 512;
            int row = f >> 3, slot = f & 7;
            const ushort_t* src = xn + (size_t)(m0 + row) * 512 + kb * 64 + ((slot ^ (row & 7)) << 3);
            gload16(src, dst + f * 8);
        }
    };
    // B K-slice: 384 rows (seg*128 + hh*64 + d) x 64 K (3072 x 16B), 6 loads/thread
    auto stageB = [&](int buf, int kb, int hp) {
        ushort_t* dst = (ushort_t*)(U + 32768 + buf * 49152);
        #pragma unroll
        for (int it = 0; it < 6; ++it) {
            int f = t + it * 512;
            int brow = f >> 3, slot = f & 7;
            int seg = brow >> 7;
            int hh = (brow >> 6) & 1;
            int d = brow & 63;
            int wrow = seg * 512 + (hp * 2 + hh) * 64 + d;
            const ushort_t* src = wq + (size_t)wrow * 512 + kb * 64 + ((slot ^ (brow & 7)) << 3);
            gload16(src, dst + f * 8);
        }
    };

    for (int hp = 0; hp < 4; ++hp) {
        __syncthreads();                     // attn of previous pass done before re-alias
        stageA(0, 0); stageB(0, 0, hp);      // 8 loads in flight

        f32x4 acc[4][6];
        #pragma unroll
        for (int a1 = 0; a1 < 4; ++a1)
            #pragma unroll
            for (int a2 = 0; a2 < 6; ++a2)
                acc[a1][a2] = (f32x4){0.f, 0.f, 0.f, 0.f};

        for (int kb = 0; kb < 8; ++kb) {
            int cur = kb & 1;
            if (kb < 7) {
                stageA(cur ^ 1, kb + 1);
                stageB(cur ^ 1, kb + 1, hp);
                asm volatile("s_waitcnt vmcnt(8)" ::: "memory");   // stage(kb) landed
            } else {
                asm volatile("s_waitcnt vmcnt(0)" ::: "memory");
            }
            wg_barrier();
            const ushort_t* Ac = (const ushort_t*)(U + cur * 16384);
            const ushort_t* Bc = (const ushort_t*)(U + 32768 + cur * 49152);
            #pragma unroll
            for (int kk = 0; kk < 2; ++kk) {
                int koff = kk * 64 + lg * 16;   // byte offset within 128B row
                s16x8 af[4];
                #pragma unroll
                for (int mf = 0; mf < 4; ++mf) {
                    int row = wm * 64 + mf * 16 + l16;
                    af[mf] = *(const s16x8*)&Ac[row * 64 + ((koff ^ ((row & 7) << 4)) >> 1)];
                }
                #pragma unroll
                for (int nh2 = 0; nh2 < 2; ++nh2) {
                    s16x8 bf[3];
                    #pragma unroll
                    for (int nf = 0; nf < 3; ++nf) {
                        int nrow = wn * 96 + (nh2 * 3 + nf) * 16 + l16;
                        bf[nf] = *(const s16x8*)&Bc[nrow * 64 + ((koff ^ ((nrow & 7) << 4)) >> 1)];
                    }
                    #pragma unroll
                    for (int mf = 0; mf < 4; ++mf)
                        #pragma unroll
                        for (int nf = 0; nf < 3; ++nf)
                            acc[mf][nh2 * 3 + nf] = __builtin_amdgcn_mfma_f32_16x16x32_bf16(
                                af[mf], bf[nf], acc[mf][nh2 * 3 + nf], 0, 0, 0);
                }
            }
            wg_barrier();                    // readers done before buffer reuse
        }

        // C-write: q/k swizzled [m][d] per head-half, V transposed [d][m]
        #pragma unroll
        for (int mf = 0; mf < 4; ++mf) {
            int mbase = wm * 64 + mf * 16 + lg * 4;
            #pragma unroll
            for (int nf = 0; nf < 6; ++nf) {
                int nn = wn * 96 + nf * 16 + l16;
                int seg = nn >> 7;
                int hh = (nn >> 6) & 1;
                int d = nn & 63;
                if (seg == 2) {
                    ushort_t* vTh = (ushort_t*)(U + 65536 + hh * 17408);
                    union { s16x4 v; ushort_t a[4]; } pk;
                    #pragma unroll
                    for (int r = 0; r < 4; ++r) pk.a[r] = f2bf(acc[mf][nf][r]);
                    *(s16x4*)&vTh[d * 136 + mbase] = pk.v;
                } else {
                    ushort_t* dst = (ushort_t*)(U + (seg ? 32768 : 0) + hh * 16384);
                    #pragma unroll
                    for (int r = 0; r < 4; ++r) {
                        int m = mbase + r;
                        dst[m * 64 + (d ^ ((m & 7) << 3))] = f2bf(acc[mf][nf][r]);
                    }
                }
            }
        }
        __syncthreads();

        // ---- attention: 16 (seq,head) pairs; wave wv = seq wv, pp = head half ----
        #pragma unroll
        for (int pp = 0; pp < 2; ++pp) {
            const ushort_t* qsmP = (const ushort_t*)(U + pp * 16384);
            const ushort_t* ksmP = (const ushort_t*)(U + 32768 + pp * 16384);
            const ushort_t* vTP  = (const ushort_t*)(U + 65536 + pp * 17408);
            int hd = hp * 2 + pp;
            int arow = wv * 16 + l16;
            int sw = (arow & 7) << 4;
            f32x4 sacc = (f32x4){0.f, 0.f, 0.f, 0.f};
            #pragma unroll
            for (int kk = 0; kk < 2; ++kk) {
                int off = kk * 64 + lg * 16;
                s16x8 ka = *(const s16x8*)&ksmP[arow * 64 + ((off ^ sw) >> 1)];
                s16x8 qb = *(const s16x8*)&qsmP[arow * 64 + ((off ^ sw) >> 1)];
                sacc = __builtin_amdgcn_mfma_f32_16x16x32_bf16(ka, qb, sacc, 0, 0, 0);
            }
            // lane holds S[j][i]: i = l16, j = lg*4+r
            const float* rbp = rb + l16 * 64 + lg * 4;
            float p[4];
            float mx = -1e30f;
            #pragma unroll
            for (int r = 0; r < 4; ++r) {
                p[r] = sacc[r] * 0.125f + rbp[r];
                mx = fmaxf(mx, p[r]);
            }
            mx = fmaxf(mx, __shfl_xor(mx, 16));
            mx = fmaxf(mx, __shfl_xor(mx, 32));
            float sum = 0.f;
            #pragma unroll
            for (int r = 0; r < 4; ++r) { p[r] = __expf(p[r] - mx); sum += p[r]; }
            sum += __shfl_xor(sum, 16);
            sum += __shfl_xor(sum, 32);
            float inv = 1.f / sum;
            {
                union { s16x4 v; ushort_t a[4]; } pk;
                #pragma unroll
                for (int r = 0; r < 4; ++r) pk.a[r] = f2bf(p[r] * inv);
                *(s16x4*)&psw[l16 * 16 + lg * 4] = pk.v;   // P[i][j]
            }
            asm volatile("s_waitcnt lgkmcnt(0)" ::: "memory");
            // PV: A = P rows i (j padded to 32 with zeros), B = vT rows d
            s16x8 ap = (s16x8){0, 0, 0, 0, 0, 0, 0, 0};
            if (lg < 2) ap = *(const s16x8*)&psw[l16 * 16 + lg * 8];
            int jj = (lg < 2) ? lg * 8 : 0;
            f32x4 ov[4];
            #pragma unroll
            for (int ff = 0; ff < 4; ++ff) {
                int d = ff * 16 + l16;
                s16x8 bv = *(const s16x8*)&vTP[d * 136 + wv * 16 + jj];
                ov[ff] = __builtin_amdgcn_mfma_f32_16x16x32_bf16(ap, bv, (f32x4){0.f, 0.f, 0.f, 0.f}, 0, 0, 0);
            }
            // stage output through this wave's private LDS rows for 16B stores
            #pragma unroll
            for (int ff = 0; ff < 4; ++ff)
                #pragma unroll
                for (int r = 0; r < 4; ++r)
                    olw[(lg * 4 + r) * 64 + ff * 16 + l16] = f2bf(ov[ff][r]);
            asm volatile("s_waitcnt lgkmcnt(0)" ::: "memory");
            {
                int i2 = lane >> 2;
                int c2 = (lane & 3) * 16;
                s16x8 w0 = *(const s16x8*)&olw[i2 * 64 + c2];
                s16x8 w1 = *(const s16x8*)&olw[i2 * 64 + c2 + 8];
                ushort_t* op = att + (size_t)(m0 + wv * 16 + i2) * 512 + hd * 64 + c2;
                *(s16x8*)op = w0;
                *(s16x8*)(op + 8) = w1;
            }
        }
    }
}

// ---------------- K3: proj GEMM + bias + residual + transpose-out ----------------
// block = (b, h, f-quad, n-half): M=128 rows, N=256, K=512. 512 threads.
// BK=32, 3-deep ring + counted vmcnt. LDS 72 KB.
__global__ __launch_bounds__(512, 2) void k_proj_out(
        const ushort_t* __restrict__ att, const ushort_t* __restrict__ wp,
        const float* __restrict__ bp, const float* __restrict__ x,
        float* __restrict__ out) {
    __shared__ __align__(16) char U[73728];   // A: 3x8192 @0, B: 3x16384 @24576
    int bid = blockIdx.x;
    int nh = bid & 1;
    int fq = (bid >> 1) & 3;
    int h = (bid >> 3) & 31;
    int b = bid >> 8;
    const int n0 = nh * 256;
    const int t = threadIdx.x;
    const int lane = t & 63;
    const int wv = t >> 6;
    const int l16 = lane & 15;
    const int lg = lane >> 4;
    const int wm = wv >> 2;   // 0..1
    const int wn = wv & 3;    // 0..3
    size_t attbase = ((size_t)(b * 32 + h) * 32) * 16 + fq * 4;  // + w*16 + fl

    auto stA = [&](int buf, int ks) {
        int row = t >> 2, slot = t & 3;
        int w = row & 31, fl = row >> 5;
        const ushort_t* src = att + (attbase + (size_t)w * 16 + fl) * 512 + ks * 32 + ((slot ^ ((row >> 2) & 3)) << 3);
        gload16(src, (ushort_t*)(U + buf * 8192) + t * 8);
    };
    auto stB = [&](int buf, int ks) {
        #pragma unroll
        for (int i = 0; i < 2; ++i) {
            int u = t + i * 512;      // 1024 units (256 rows x 4 slots)
            int row = u >> 2, slot = u & 3;
            const ushort_t* src = wp + (size_t)(n0 + row) * 512 + ks * 32 + ((slot ^ ((row >> 2) & 3)) << 3);
            gload16(src, (ushort_t*)(U + 24576 + buf * 16384) + u * 8);
        }
    };

    f32x4 acc[4][4];
    #pragma unroll
    for (int m = 0; m < 4; ++m)
        #pragma unroll
        for (int n = 0; n < 4; ++n)
            acc[m][n] = (f32x4){0.f, 0.f, 0.f, 0.f};

    stA(0, 0); stB(0, 0);    // 3 loads
    stA(1, 1); stB(1, 1);    // 3 loads -> 6 in flight
    for (int ks = 0; ks < 16; ++ks) {
        int cur = ks % 3;
        if (ks < 14) {
            stA((ks + 2) % 3, ks + 2);
            stB((ks + 2) % 3, ks + 2);
            asm volatile("s_waitcnt vmcnt(6)" ::: "memory");
        } else if (ks == 14) {
            asm volatile("s_waitcnt vmcnt(3)" ::: "memory");
        } else {
            asm volatile("s_waitcnt vmcnt(0)" ::: "memory");
        }
        wg_barrier();
        s16x8 af[4], bf[4];
        #pragma unroll
        for (int mf = 0; mf < 4; ++mf) {
            int row = wm * 64 + mf * 16 + l16;
            af[mf] = *(const s16x8*)((ushort_t*)(U + cur * 8192) + row * 32 + ((lg ^ ((row >> 2) & 3)) << 3));
        }
        #pragma unroll
        for (int nf = 0; nf < 4; ++nf) {
            int nrow = wn * 64 + nf * 16 + l16;
            bf[nf] = *(const s16x8*)((ushort_t*)(U + 24576 + cur * 16384) + nrow * 32 + ((lg ^ ((nrow >> 2) & 3)) << 3));
        }
        #pragma unroll
        for (int mf = 0; mf < 4; ++mf)
            #pragma unroll
            for (int nf = 0; nf < 4; ++nf)
                acc[mf][nf] = __builtin_amdgcn_mfma_f32_16x16x32_bf16(bf[nf], af[mf], acc[mf][nf], 0, 0, 0);
        wg_barrier();
    }

    // epilogue: direct stores, bias + residual fused (D: col l16 = M, row lg*4+r = N)
    size_t obase = (size_t)b * SB + (size_t)(fq * 4) * SF + h * 32;
    #pragma unroll
    for (int mf = 0; mf < 4; ++mf) {
        int m = wm * 64 + mf * 16 + l16;
        int w = m & 31, fl = m >> 5;
        size_t base_m = obase + (size_t)fl * SF + w;
        #pragma unroll
        for (int nf = 0; nf < 4; ++nf) {
            int col0 = n0 + wn * 64 + nf * 16 + lg * 4;
            #pragma unroll
            for (int r = 0; r < 4; ++r) {
                int col = col0 + r;
                size_t a = base_m + (size_t)col * SC;
                out[a] = acc[mf][nf][r] + bp[col] + x[a];
            }
        }
    }
}

extern "C" void kernel_launch(void* const* d_in, const int* in_sizes, int n_in,
                              void* d_out, int out_size, void* d_ws, size_t ws_size,
                              hipStream_t stream) {
    const float* x     = (const float*)d_in[0];
    const float* wqkv  = (const float*)d_in[1];
    const float* wproj = (const float*)d_in[2];
    const float* bproj = (const float*)d_in[3];
    const float* rb    = (const float*)d_in[4];
    const float* lng   = (const float*)d_in[5];
    const float* lnb   = (const float*)d_in[6];
    float* out = (float*)d_out;
    char* ws = (char*)d_ws;
    ushort_t* xn   = (ushort_t*)(ws);                  // 64 MB
    ushort_t* att  = (ushort_t*)(ws + 67108864);       // 64 MB
    ushort_t* wq16 = (ushort_t*)(ws + 134217728);      // 1.5 MB
    ushort_t* wp16 = (ushort_t*)(ws + 135790592);      // 0.5 MB

    k_cvt<<<3072, 256, 0, stream>>>(wqkv, 1536 * 512, wproj, 512 * 512, wq16, wp16);
    k_ln_transpose<<<2048, 256, 0, stream>>>(x, lng, lnb, xn);
    k_qkv_attn<<<512, 512, 0, stream>>>(xn, wq16, rb, att);
    k_proj_out<<<1024, 512, 0, stream>>>(att, wp16, bproj, x, out);
}

// Round 12
// 333.530 us; speedup vs baseline: 1.4695x; 1.3760x over previous
//
#include <hip/hip_runtime.h>

typedef unsigned short ushort_t;
typedef __attribute__((ext_vector_type(4))) float f32x4;
typedef __attribute__((ext_vector_type(8))) short s16x8;
typedef __attribute__((ext_vector_type(4))) short s16x4;

#define SB 8388608   // x batch stride (512*16*32*32)
#define SC 16384     // x channel stride (16*32*32)
#define SF 1024      // x frame stride (32*32)

static __device__ __forceinline__ float bf2f(ushort_t u) {
    union { float f; unsigned int i; } x; x.i = ((unsigned int)u) << 16; return x.f;
}
static __device__ __forceinline__ ushort_t f2bf(float f) {
    union { float f; unsigned int i; } x; x.f = f;
    unsigned int u = x.i;
    unsigned int r = (u + 0x7FFFu + ((u >> 16) & 1u)) >> 16;
    return (ushort_t)r;
}

static __device__ __forceinline__ void gload16(const void* g, void* l) {
    __builtin_amdgcn_global_load_lds(
        (const __attribute__((address_space(1))) unsigned int*)g,
        (__attribute__((address_space(3))) unsigned int*)l, 16, 0, 0);
}

// raw barrier (used only in k_proj_out's proven loop)
static __device__ __forceinline__ void wg_barrier() {
    asm volatile("" ::: "memory");
    __builtin_amdgcn_s_barrier();
    asm volatile("" ::: "memory");
}

// ---------------- K0: convert weights to bf16 ----------------
__global__ void k_cvt(const float* __restrict__ a, int n1,
                      const float* __restrict__ b, int n2,
                      ushort_t* __restrict__ o1, ushort_t* __restrict__ o2) {
    int i = blockIdx.x * blockDim.x + threadIdx.x;
    if (i < n1) o1[i] = f2bf(a[i]);
    if (i < n2) o2[i] = f2bf(b[i]);
}

// ---------------- K1: LayerNorm + transpose -> xn (65536 x 512) bf16 ----------------
__global__ __launch_bounds__(256) void k_ln_transpose(
        const float* __restrict__ x, const float* __restrict__ g,
        const float* __restrict__ bta, ushort_t* __restrict__ xn) {
    __shared__ float tile[32 * 513];
    __shared__ float gg[512];
    __shared__ float bb[512];
    int bid = blockIdx.x;
    int b = bid >> 9;
    int f = (bid >> 5) & 15;
    int h = bid & 31;
    int t = threadIdx.x;
    for (int c = t; c < 512; c += 256) { gg[c] = g[c]; bb[c] = bta[c]; }
    const float* xp = x + (size_t)b * SB + (size_t)f * SF + h * 32;
    int wq4 = (t & 7) * 4;
    int c0 = t >> 3;
    for (int it = 0; it < 16; ++it) {
        int c = c0 + it * 32;
        f32x4 v = *(const f32x4*)(xp + (size_t)c * SC + wq4);
        tile[(wq4 + 0) * 513 + c] = v[0];
        tile[(wq4 + 1) * 513 + c] = v[1];
        tile[(wq4 + 2) * 513 + c] = v[2];
        tile[(wq4 + 3) * 513 + c] = v[3];
    }
    __syncthreads();
    int lane = t & 63;
    int wave = t >> 6;
    for (int wi = 0; wi < 8; ++wi) {
        int ww = wave * 8 + wi;
        float s = 0.f, s2 = 0.f;
        #pragma unroll
        for (int j = 0; j < 8; ++j) {
            float v = tile[ww * 513 + lane + j * 64];
            s += v; s2 += v * v;
        }
        #pragma unroll
        for (int off = 32; off; off >>= 1) { s += __shfl_xor(s, off); s2 += __shfl_xor(s2, off); }
        float mean = s * (1.f / 512.f);
        float var = s2 * (1.f / 512.f) - mean * mean;
        float rstd = rsqrtf(var + 1e-5f);
        size_t row = ((size_t)((b * 32 + h) * 32 + ww)) * 16 + f;
        ushort_t* op = xn + row * 512 + lane * 8;
        union { ushort_t a[8]; s16x8 v; } u;
        #pragma unroll
        for (int j = 0; j < 8; ++j) {
            int c = lane * 8 + j;
            float v = tile[ww * 513 + c];
            u.a[j] = f2bf((v - mean) * rstd * gg[c] + bb[c]);
        }
        *(s16x8*)op = u.v;
    }
}

// ---------------- K2: fused QKV GEMM + attention ----------------
// 256 threads (4 waves), block = 4 sequences (64 rows), grid 1024.
// Per head: GEMM 64x192, wave tile 64x48 (acc[4][3]). BK=64 dbuf.
// CONSERVATIVE SYNC this round: plain __syncthreads() per kb (full drain) —
// validates the 256-thread indexing and isolates the 2-blocks/CU effect.
// LDS 64 KB -> 2 blocks/CU; drain stalls covered by the co-resident block.
__global__ __launch_bounds__(256, 2) void k_qkv_attn(
        const ushort_t* __restrict__ xn, const ushort_t* __restrict__ wq,
        const float* __restrict__ rb, ushort_t* __restrict__ att) {
    __shared__ __align__(16) char U[65536];
    // staging: A buf i @ i*8192 (8 KB); B buf i @ 16384 + i*24576 (24 KB)
    // attn alias: qsm@0 [64][64] swz, ksm@8192, vT@16384 [64 d][72 m],
    //             ps@25600 (4x256 us), ol@27648 (4x1024 us)

    const int t = threadIdx.x;
    const int lane = t & 63;
    const int wv = t >> 6;          // 0..3 = N quarter AND attn seq
    const int l16 = lane & 15;
    const int lg = lane >> 4;
    const int m0 = blockIdx.x * 64;
    ushort_t* qsm = (ushort_t*)(U);
    ushort_t* ksm = (ushort_t*)(U + 8192);
    ushort_t* vT  = (ushort_t*)(U + 16384);
    ushort_t* psw = (ushort_t*)(U + 25600) + wv * 256;
    ushort_t* olw = (ushort_t*)(U + 27648) + wv * 1024;

    // A K-slice: 64 rows x 64 K (512 x 16B), 2 loads/thread
    auto stageA = [&](int buf, int kb) {
        ushort_t* dst = (ushort_t*)(U + buf * 8192);
        #pragma unroll
        for (int it = 0; it < 2; ++it) {
            int f = t + it * 256;
            int row = f >> 3, slot = f & 7;
            const ushort_t* src = xn + (size_t)(m0 + row) * 512 + kb * 64 + ((slot ^ (row & 7)) << 3);
            gload16(src, dst + f * 8);
        }
    };
    // B K-slice: 192 rows x 64 K (1536 x 16B), 6 loads/thread
    auto stageB = [&](int buf, int kb, int h) {
        ushort_t* dst = (ushort_t*)(U + 16384 + buf * 24576);
        #pragma unroll
        for (int it = 0; it < 6; ++it) {
            int f = t + it * 256;
            int brow = f >> 3, slot = f & 7;
            int seg = brow >> 6;           // 0=q,1=k,2=v
            int wrow = seg * 512 + h * 64 + (brow & 63);
            const ushort_t* src = wq + (size_t)wrow * 512 + kb * 64 + ((slot ^ (brow & 7)) << 3);
            gload16(src, dst + f * 8);
        }
    };

    for (int h = 0; h < 8; ++h) {
        __syncthreads();                     // attn of h-1 done before re-alias
        stageA(0, 0); stageB(0, 0, h);       // prologue stage (drained by loop's first sync)

        f32x4 acc[4][3];
        #pragma unroll
        for (int a1 = 0; a1 < 4; ++a1)
            #pragma unroll
            for (int a2 = 0; a2 < 3; ++a2)
                acc[a1][a2] = (f32x4){0.f, 0.f, 0.f, 0.f};

        for (int kb = 0; kb < 8; ++kb) {
            int cur = kb & 1;
            if (kb < 7) { stageA(cur ^ 1, kb + 1); stageB(cur ^ 1, kb + 1, h); }
            __syncthreads();                 // full drain: kb's data resident
            const ushort_t* Ac = (const ushort_t*)(U + cur * 8192);
            const ushort_t* Bc = (const ushort_t*)(U + 16384 + cur * 24576);
            #pragma unroll
            for (int kk = 0; kk < 2; ++kk) {
                int koff = kk * 64 + lg * 16;   // byte offset within 128B row
                s16x8 af[4], bf[3];
                #pragma unroll
                for (int mf = 0; mf < 4; ++mf) {
                    int row = mf * 16 + l16;
                    af[mf] = *(const s16x8*)&Ac[row * 64 + ((koff ^ ((row & 7) << 4)) >> 1)];
                }
                #pragma unroll
                for (int nf = 0; nf < 3; ++nf) {
                    int nrow = wv * 48 + nf * 16 + l16;
                    bf[nf] = *(const s16x8*)&Bc[nrow * 64 + ((koff ^ ((nrow & 7) << 4)) >> 1)];
                }
                #pragma unroll
                for (int mf = 0; mf < 4; ++mf)
                    #pragma unroll
                    for (int nf = 0; nf < 3; ++nf)
                        acc[mf][nf] = __builtin_amdgcn_mfma_f32_16x16x32_bf16(af[mf], bf[nf], acc[mf][nf], 0, 0, 0);
            }
            __syncthreads();                 // readers done before buffer reuse
        }

        // C-write: q/k swizzled [m][d], V transposed [d][m] (aliases staging)
        #pragma unroll
        for (int mf = 0; mf < 4; ++mf) {
            int mbase = mf * 16 + lg * 4;
            #pragma unroll
            for (int nf = 0; nf < 3; ++nf) {
                int nn = wv * 48 + nf * 16 + l16;
                int seg = nn >> 6;
                int d = nn & 63;
                if (seg == 2) {
                    union { s16x4 v; ushort_t a[4]; } pk;
                    #pragma unroll
                    for (int r = 0; r < 4; ++r) pk.a[r] = f2bf(acc[mf][nf][r]);
                    *(s16x4*)&vT[d * 72 + mbase] = pk.v;
                } else {
                    ushort_t* dst = seg ? ksm : qsm;
                    #pragma unroll
                    for (int r = 0; r < 4; ++r) {
                        int m = mbase + r;
                        dst[m * 64 + (d ^ ((m & 7) << 3))] = f2bf(acc[mf][nf][r]);
                    }
                }
            }
        }
        __syncthreads();

        // ---- attention: wave wv handles sequence wv (16 rows) ----
        {
            int arow = wv * 16 + l16;
            int sw = (arow & 7) << 4;
            f32x4 sacc = (f32x4){0.f, 0.f, 0.f, 0.f};
            #pragma unroll
            for (int kk = 0; kk < 2; ++kk) {
                int off = kk * 64 + lg * 16;
                s16x8 ka = *(const s16x8*)&ksm[arow * 64 + ((off ^ sw) >> 1)];
                s16x8 qb = *(const s16x8*)&qsm[arow * 64 + ((off ^ sw) >> 1)];
                sacc = __builtin_amdgcn_mfma_f32_16x16x32_bf16(ka, qb, sacc, 0, 0, 0);
            }
            // lane holds S[j][i]: i = l16, j = lg*4+r
            const float* rbp = rb + l16 * 64 + lg * 4;
            float p[4];
            float mx = -1e30f;
            #pragma unroll
            for (int r = 0; r < 4; ++r) {
                p[r] = sacc[r] * 0.125f + rbp[r];
                mx = fmaxf(mx, p[r]);
            }
            mx = fmaxf(mx, __shfl_xor(mx, 16));
            mx = fmaxf(mx, __shfl_xor(mx, 32));
            float sum = 0.f;
            #pragma unroll
            for (int r = 0; r < 4; ++r) { p[r] = __expf(p[r] - mx); sum += p[r]; }
            sum += __shfl_xor(sum, 16);
            sum += __shfl_xor(sum, 32);
            float inv = 1.f / sum;
            {
                union { s16x4 v; ushort_t a[4]; } pk;
                #pragma unroll
                for (int r = 0; r < 4; ++r) pk.a[r] = f2bf(p[r] * inv);
                *(s16x4*)&psw[l16 * 16 + lg * 4] = pk.v;   // P[i][j]
            }
            __syncthreads();
            // PV: A = P rows i (j padded to 32 with zeros), B = vT rows d
            s16x8 ap = (s16x8){0, 0, 0, 0, 0, 0, 0, 0};
            if (lg < 2) ap = *(const s16x8*)&psw[l16 * 16 + lg * 8];
            int jj = (lg < 2) ? lg * 8 : 0;
            f32x4 ov[4];
            #pragma unroll
            for (int ff = 0; ff < 4; ++ff) {
                int d = ff * 16 + l16;
                s16x8 bv = *(const s16x8*)&vT[d * 72 + wv * 16 + jj];
                ov[ff] = __builtin_amdgcn_mfma_f32_16x16x32_bf16(ap, bv, (f32x4){0.f, 0.f, 0.f, 0.f}, 0, 0, 0);
            }
            // stage output through this wave's private LDS rows for 16B stores
            #pragma unroll
            for (int ff = 0; ff < 4; ++ff)
                #pragma unroll
                for (int r = 0; r < 4; ++r)
                    olw[(lg * 4 + r) * 64 + ff * 16 + l16] = f2bf(ov[ff][r]);
            __syncthreads();
            {
                int i2 = lane >> 2;
                int c2 = (lane & 3) * 16;
                s16x8 w0 = *(const s16x8*)&olw[i2 * 64 + c2];
                s16x8 w1 = *(const s16x8*)&olw[i2 * 64 + c2 + 8];
                ushort_t* op = att + (size_t)(m0 + wv * 16 + i2) * 512 + h * 64 + c2;
                *(s16x8*)op = w0;
                *(s16x8*)(op + 8) = w1;
            }
        }
    }
}

// ---------------- K3: proj GEMM + bias + residual + transpose-out ----------------
// block = (b, h, f-quad, n-half): M=128 rows, N=256, K=512. 512 threads.
// BK=32, 3-deep ring + counted vmcnt. LDS 72 KB. (passing since round 7)
__global__ __launch_bounds__(512, 2) void k_proj_out(
        const ushort_t* __restrict__ att, const ushort_t* __restrict__ wp,
        const float* __restrict__ bp, const float* __restrict__ x,
        float* __restrict__ out) {
    __shared__ __align__(16) char U[73728];   // A: 3x8192 @0, B: 3x16384 @24576
    int bid = blockIdx.x;
    int nh = bid & 1;
    int fq = (bid >> 1) & 3;
    int h = (bid >> 3) & 31;
    int b = bid >> 8;
    const int n0 = nh * 256;
    const int t = threadIdx.x;
    const int lane = t & 63;
    const int wv = t >> 6;
    const int l16 = lane & 15;
    const int lg = lane >> 4;
    const int wm = wv >> 2;   // 0..1
    const int wn = wv & 3;    // 0..3
    size_t attbase = ((size_t)(b * 32 + h) * 32) * 16 + fq * 4;  // + w*16 + fl

    auto stA = [&](int buf, int ks) {
        int row = t >> 2, slot = t & 3;
        int w = row & 31, fl = row >> 5;
        const ushort_t* src = att + (attbase + (size_t)w * 16 + fl) * 512 + ks * 32 + ((slot ^ ((row >> 2) & 3)) << 3);
        gload16(src, (ushort_t*)(U + buf * 8192) + t * 8);
    };
    auto stB = [&](int buf, int ks) {
        #pragma unroll
        for (int i = 0; i < 2; ++i) {
            int u = t + i * 512;      // 1024 units (256 rows x 4 slots)
            int row = u >> 2, slot = u & 3;
            const ushort_t* src = wp + (size_t)(n0 + row) * 512 + ks * 32 + ((slot ^ ((row >> 2) & 3)) << 3);
            gload16(src, (ushort_t*)(U + 24576 + buf * 16384) + u * 8);
        }
    };

    f32x4 acc[4][4];
    #pragma unroll
    for (int m = 0; m < 4; ++m)
        #pragma unroll
        for (int n = 0; n < 4; ++n)
            acc[m][n] = (f32x4){0.f, 0.f, 0.f, 0.f};

    stA(0, 0); stB(0, 0);    // 3 loads
    stA(1, 1); stB(1, 1);    // 3 loads -> 6 in flight
    for (int ks = 0; ks < 16; ++ks) {
        int cur = ks % 3;
        if (ks < 14) {
            stA((ks + 2) % 3, ks + 2);
            stB((ks + 2) % 3, ks + 2);
            asm volatile("s_waitcnt vmcnt(6)" ::: "memory");
        } else if (ks == 14) {
            asm volatile("s_waitcnt vmcnt(3)" ::: "memory");
        } else {
            asm volatile("s_waitcnt vmcnt(0)" ::: "memory");
        }
        wg_barrier();
        s16x8 af[4], bf[4];
        #pragma unroll
        for (int mf = 0; mf < 4; ++mf) {
            int row = wm * 64 + mf * 16 + l16;
            af[mf] = *(const s16x8*)((ushort_t*)(U + cur * 8192) + row * 32 + ((lg ^ ((row >> 2) & 3)) << 3));
        }
        #pragma unroll
        for (int nf = 0; nf < 4; ++nf) {
            int nrow = wn * 64 + nf * 16 + l16;
            bf[nf] = *(const s16x8*)((ushort_t*)(U + 24576 + cur * 16384) + nrow * 32 + ((lg ^ ((nrow >> 2) & 3)) << 3));
        }
        #pragma unroll
        for (int mf = 0; mf < 4; ++mf)
            #pragma unroll
            for (int nf = 0; nf < 4; ++nf)
                acc[mf][nf] = __builtin_amdgcn_mfma_f32_16x16x32_bf16(bf[nf], af[mf], acc[mf][nf], 0, 0, 0);
        wg_barrier();
    }

    // epilogue: direct stores, bias + residual fused (D: col l16 = M, row lg*4+r = N)
    size_t obase = (size_t)b * SB + (size_t)(fq * 4) * SF + h * 32;
    #pragma unroll
    for (int mf = 0; mf < 4; ++mf) {
        int m = wm * 64 + mf * 16 + l16;
        int w = m & 31, fl = m >> 5;
        size_t base_m = obase + (size_t)fl * SF + w;
        #pragma unroll
        for (int nf = 0; nf < 4; ++nf) {
            int col0 = n0 + wn * 64 + nf * 16 + lg * 4;
            #pragma unroll
            for (int r = 0; r < 4; ++r) {
                int col = col0 + r;
                size_t a = base_m + (size_t)col * SC;
                out[a] = acc[mf][nf][r] + bp[col] + x[a];
            }
        }
    }
}

extern "C" void kernel_launch(void* const* d_in, const int* in_sizes, int n_in,
                              void* d_out, int out_size, void* d_ws, size_t ws_size,
                              hipStream_t stream) {
    const float* x     = (const float*)d_in[0];
    const float* wqkv  = (const float*)d_in[1];
    const float* wproj = (const float*)d_in[2];
    const float* bproj = (const float*)d_in[3];
    const float* rb    = (const float*)d_in[4];
    const float* lng   = (const float*)d_in[5];
    const float* lnb   = (const float*)d_in[6];
    float* out = (float*)d_out;
    char* ws = (char*)d_ws;
    ushort_t* xn   = (ushort_t*)(ws);                  // 64 MB
    ushort_t* att  = (ushort_t*)(ws + 67108864);       // 64 MB
    ushort_t* wq16 = (ushort_t*)(ws + 134217728);      // 1.5 MB
    ushort_t* wp16 = (ushort_t*)(ws + 135790592);      // 0.5 MB

    k_cvt<<<3072, 256, 0, stream>>>(wqkv, 1536 * 512, wproj, 512 * 512, wq16, wp16);
    k_ln_transpose<<<2048, 256, 0, stream>>>(x, lng, lnb, xn);
    k_qkv_attn<<<1024, 256, 0, stream>>>(xn, wq16, rb, att);
    k_proj_out<<<1024, 512, 0, stream>>>(att, wp16, bproj, x, out);
}

// Round 13
// 327.621 us; speedup vs baseline: 1.4960x; 1.0180x over previous
//
#include <hip/hip_runtime.h>

typedef unsigned short ushort_t;
typedef __attribute__((ext_vector_type(4))) float f32x4;
typedef __attribute__((ext_vector_type(8))) short s16x8;
typedef __attribute__((ext_vector_type(4))) short s16x4;

#define SB 8388608   // x batch stride (512*16*32*32)
#define SC 16384     // x channel stride (16*32*32)
#define SF 1024      // x frame stride (32*32)

static __device__ __forceinline__ float bf2f(ushort_t u) {
    union { float f; unsigned int i; } x; x.i = ((unsigned int)u) << 16; return x.f;
}
static __device__ __forceinline__ ushort_t f2bf(float f) {
    union { float f; unsigned int i; } x; x.f = f;
    unsigned int u = x.i;
    unsigned int r = (u + 0x7FFFu + ((u >> 16) & 1u)) >> 16;
    return (ushort_t)r;
}

static __device__ __forceinline__ void gload16(const void* g, void* l) {
    __builtin_amdgcn_global_load_lds(
        (const __attribute__((address_space(1))) unsigned int*)g,
        (__attribute__((address_space(3))) unsigned int*)l, 16, 0, 0);
}

// raw barrier: no implicit vmcnt(0) drain
static __device__ __forceinline__ void wg_barrier() {
    asm volatile("" ::: "memory");
    __builtin_amdgcn_s_barrier();
    asm volatile("" ::: "memory");
}

// ---------------- K0: convert weights to bf16 ----------------
__global__ void k_cvt(const float* __restrict__ a, int n1,
                      const float* __restrict__ b, int n2,
                      ushort_t* __restrict__ o1, ushort_t* __restrict__ o2) {
    int i = blockIdx.x * blockDim.x + threadIdx.x;
    if (i < n1) o1[i] = f2bf(a[i]);
    if (i < n2) o2[i] = f2bf(b[i]);
}

// ---------------- K1: LayerNorm + transpose -> xn (65536 x 512) bf16 ----------------
__global__ __launch_bounds__(256) void k_ln_transpose(
        const float* __restrict__ x, const float* __restrict__ g,
        const float* __restrict__ bta, ushort_t* __restrict__ xn) {
    __shared__ float tile[32 * 513];
    __shared__ float gg[512];
    __shared__ float bb[512];
    int bid = blockIdx.x;
    int b = bid >> 9;
    int f = (bid >> 5) & 15;
    int h = bid & 31;
    int t = threadIdx.x;
    for (int c = t; c < 512; c += 256) { gg[c] = g[c]; bb[c] = bta[c]; }
    const float* xp = x + (size_t)b * SB + (size_t)f * SF + h * 32;
    int wq4 = (t & 7) * 4;
    int c0 = t >> 3;
    for (int it = 0; it < 16; ++it) {
        int c = c0 + it * 32;
        f32x4 v = *(const f32x4*)(xp + (size_t)c * SC + wq4);
        tile[(wq4 + 0) * 513 + c] = v[0];
        tile[(wq4 + 1) * 513 + c] = v[1];
        tile[(wq4 + 2) * 513 + c] = v[2];
        tile[(wq4 + 3) * 513 + c] = v[3];
    }
    __syncthreads();
    int lane = t & 63;
    int wave = t >> 6;
    for (int wi = 0; wi < 8; ++wi) {
        int ww = wave * 8 + wi;
        float s = 0.f, s2 = 0.f;
        #pragma unroll
        for (int j = 0; j < 8; ++j) {
            float v = tile[ww * 513 + lane + j * 64];
            s += v; s2 += v * v;
        }
        #pragma unroll
        for (int off = 32; off; off >>= 1) { s += __shfl_xor(s, off); s2 += __shfl_xor(s2, off); }
        float mean = s * (1.f / 512.f);
        float var = s2 * (1.f / 512.f) - mean * mean;
        float rstd = rsqrtf(var + 1e-5f);
        size_t row = ((size_t)((b * 32 + h) * 32 + ww)) * 16 + f;
        ushort_t* op = xn + row * 512 + lane * 8;
        union { ushort_t a[8]; s16x8 v; } u;
        #pragma unroll
        for (int j = 0; j < 8; ++j) {
            int c = lane * 8 + j;
            float v = tile[ww * 513 + c];
            u.a[j] = f2bf((v - mean) * rstd * gg[c] + bb[c]);
        }
        *(s16x8*)op = u.v;
    }
}

// ---------------- K2: fused QKV GEMM + attention (round-7 proven: 173 us) ----
// block = 8 sequences (128 rows), 512 threads (8 waves). BK=64, 3-deep
// staging ring with 2-ahead prefetch + counted vmcnt (no drain-0 in loop).
__global__ __launch_bounds__(512) void k_qkv_attn(
        const ushort_t* __restrict__ xn, const ushort_t* __restrict__ wq,
        const float* __restrict__ rb, ushort_t* __restrict__ att) {
    __shared__ __align__(16) char U[122880];
    // staging ring: A buf i @ U + i*16384 (i<3); B buf i @ U + 49152 + i*24576
    // attention layout (aliases ring):
    ushort_t* qsm = (ushort_t*)(U);            // 16384 B [128 m][64 d] swz
    ushort_t* ksm = (ushort_t*)(U + 16384);    // 16384 B
    ushort_t* vT  = (ushort_t*)(U + 32768);    // 17408 B [64 d][136 m]

    const int t = threadIdx.x;
    const int lane = t & 63;
    const int wv = t >> 6;
    const int l16 = lane & 15;
    const int lg = lane >> 4;
    const int m0 = blockIdx.x * 128;
    const int wm = wv >> 2;   // 0..1  (M half)
    const int wn = wv & 3;    // 0..3  (N quarter)
    ushort_t* psw = ksm + wv * 1024;   // per-wave P scratch
    ushort_t* olw = qsm + wv * 1024;   // per-wave out-stage scratch

    // A K-slice: 128 rows x 64 K (16384 B = 1024 x 16B), 2 loads/thread
    auto stageA = [&](int buf, int kb) {
        ushort_t* dst = (ushort_t*)(U + buf * 16384);
        #pragma unroll
        for (int it = 0; it < 2; ++it) {
            int f = t + it * 512;
            int row = f >> 3, slot = f & 7;
            const ushort_t* src = xn + (size_t)(m0 + row) * 512 + kb * 64 + ((slot ^ (row & 7)) << 3);
            gload16(src, dst + f * 8);
        }
    };
    // B K-slice: 192 rows x 64 K (24576 B = 1536 x 16B), 3 loads/thread
    auto stageB = [&](int buf, int kb, int h) {
        ushort_t* dst = (ushort_t*)(U + 49152 + buf * 24576);
        #pragma unroll
        for (int it = 0; it < 3; ++it) {
            int f = t + it * 512;
            int brow = f >> 3, slot = f & 7;
            int wrow = (brow >> 6) * 512 + h * 64 + (brow & 63);
            const ushort_t* src = wq + (size_t)wrow * 512 + kb * 64 + ((slot ^ (brow & 7)) << 3);
            gload16(src, dst + f * 8);
        }
    };

    for (int h = 0; h < 8; ++h) {
        __syncthreads();                     // attn of h-1 fully done before ring reuse
        stageA(0, 0); stageB(0, 0, h);       // kb=0  (5 loads)
        stageA(1, 1); stageB(1, 1, h);       // kb=1  (5 loads) -> 10 in flight

        f32x4 acc[4][3];
        #pragma unroll
        for (int a1 = 0; a1 < 4; ++a1)
            #pragma unroll
            for (int a2 = 0; a2 < 3; ++a2)
                acc[a1][a2] = (f32x4){0.f, 0.f, 0.f, 0.f};

        for (int kb = 0; kb < 8; ++kb) {
            int cur = kb % 3;
            if (kb < 6) {
                stageA((kb + 2) % 3, kb + 2);
                stageB((kb + 2) % 3, kb + 2, h);
                asm volatile("s_waitcnt vmcnt(10)" ::: "memory");  // stage(kb) done
            } else if (kb == 6) {
                asm volatile("s_waitcnt vmcnt(5)" ::: "memory");
            } else {
                asm volatile("s_waitcnt vmcnt(0)" ::: "memory");
            }
            wg_barrier();                    // all waves' stage(kb) visible
            const ushort_t* Ac = (const ushort_t*)(U + cur * 16384);
            const ushort_t* Bc = (const ushort_t*)(U + 49152 + cur * 24576);
            #pragma unroll
            for (int kk = 0; kk < 2; ++kk) {
                int koff = kk * 64 + lg * 16;   // byte offset within 128B row
                s16x8 af[4], bf[3];
                #pragma unroll
                for (int mf = 0; mf < 4; ++mf) {
                    int row = wm * 64 + mf * 16 + l16;
                    af[mf] = *(const s16x8*)&Ac[row * 64 + ((koff ^ ((row & 7) << 4)) >> 1)];
                }
                #pragma unroll
                for (int nf = 0; nf < 3; ++nf) {
                    int nrow = wn * 48 + nf * 16 + l16;
                    bf[nf] = *(const s16x8*)&Bc[nrow * 64 + ((koff ^ ((nrow & 7) << 4)) >> 1)];
                }
                #pragma unroll
                for (int mf = 0; mf < 4; ++mf)
                    #pragma unroll
                    for (int nf = 0; nf < 3; ++nf)
                        acc[mf][nf] = __builtin_amdgcn_mfma_f32_16x16x32_bf16(af[mf], bf[nf], acc[mf][nf], 0, 0, 0);
            }
            wg_barrier();                    // readers done before ring slot reuse
        }

        // C-write: q/k swizzled [m][d], V transposed [d][m] (aliases ring)
        #pragma unroll
        for (int mf = 0; mf < 4; ++mf) {
            int mbase = wm * 64 + mf * 16 + lg * 4;
            #pragma unroll
            for (int nf = 0; nf < 3; ++nf) {
                int nn = wn * 48 + nf * 16 + l16;
                int seg = nn >> 6;
                int d = nn & 63;
                if (seg == 2) {
                    union { s16x4 v; ushort_t a[4]; } pk;
                    #pragma unroll
                    for (int r = 0; r < 4; ++r) pk.a[r] = f2bf(acc[mf][nf][r]);
                    *(s16x4*)&vT[d * 136 + mbase] = pk.v;
                } else {
                    ushort_t* dst = seg ? ksm : qsm;
                    #pragma unroll
                    for (int r = 0; r < 4; ++r) {
                        int m = mbase + r;
                        dst[m * 64 + (d ^ ((m & 7) << 3))] = f2bf(acc[mf][nf][r]);
                    }
                }
            }
        }
        __syncthreads();

        // ---- attention: wave wv handles sequence wv (16 rows) ----
        {
            int arow = wv * 16 + l16;
            int sw = (arow & 7) << 4;
            f32x4 sacc = (f32x4){0.f, 0.f, 0.f, 0.f};
            #pragma unroll
            for (int kk = 0; kk < 2; ++kk) {
                int off = kk * 64 + lg * 16;
                s16x8 ka = *(const s16x8*)&ksm[arow * 64 + ((off ^ sw) >> 1)];
                s16x8 qb = *(const s16x8*)&qsm[arow * 64 + ((off ^ sw) >> 1)];
                sacc = __builtin_amdgcn_mfma_f32_16x16x32_bf16(ka, qb, sacc, 0, 0, 0);
            }
            // lane holds S[j][i]: i = l16, j = lg*4+r
            const float* rbp = rb + l16 * 64 + lg * 4;
            float p[4];
            float mx = -1e30f;
            #pragma unroll
            for (int r = 0; r < 4; ++r) {
                p[r] = sacc[r] * 0.125f + rbp[r];
                mx = fmaxf(mx, p[r]);
            }
            mx = fmaxf(mx, __shfl_xor(mx, 16));
            mx = fmaxf(mx, __shfl_xor(mx, 32));
            float sum = 0.f;
            #pragma unroll
            for (int r = 0; r < 4; ++r) { p[r] = __expf(p[r] - mx); sum += p[r]; }
            sum += __shfl_xor(sum, 16);
            sum += __shfl_xor(sum, 32);
            float inv = 1.f / sum;
            {
                union { s16x4 v; ushort_t a[4]; } pk;
                #pragma unroll
                for (int r = 0; r < 4; ++r) pk.a[r] = f2bf(p[r] * inv);
                *(s16x4*)&psw[l16 * 16 + lg * 4] = pk.v;   // P[i][j]
            }
            asm volatile("s_waitcnt lgkmcnt(0)" ::: "memory");
            // PV: A = P rows i (j padded to 32 with zeros), B = vT rows d
            s16x8 ap = (s16x8){0, 0, 0, 0, 0, 0, 0, 0};
            if (lg < 2) ap = *(const s16x8*)&psw[l16 * 16 + lg * 8];
            int jj = (lg < 2) ? lg * 8 : 0;
            f32x4 ov[4];
            #pragma unroll
            for (int ff = 0; ff < 4; ++ff) {
                int d = ff * 16 + l16;
                s16x8 bv = *(const s16x8*)&vT[d * 136 + wv * 16 + jj];
                ov[ff] = __builtin_amdgcn_mfma_f32_16x16x32_bf16(ap, bv, (f32x4){0.f, 0.f, 0.f, 0.f}, 0, 0, 0);
            }
            // stage output through this wave's private LDS rows for 16B stores
            #pragma unroll
            for (int ff = 0; ff < 4; ++ff)
                #pragma unroll
                for (int r = 0; r < 4; ++r)
                    olw[(lg * 4 + r) * 64 + ff * 16 + l16] = f2bf(ov[ff][r]);
            asm volatile("s_waitcnt lgkmcnt(0)" ::: "memory");
            {
                int i2 = lane >> 2;
                int c2 = (lane & 3) * 16;
                s16x8 w0 = *(const s16x8*)&olw[i2 * 64 + c2];
                s16x8 w1 = *(const s16x8*)&olw[i2 * 64 + c2 + 8];
                ushort_t* op = att + (size_t)(m0 + wv * 16 + i2) * 512 + h * 64 + c2;
                *(s16x8*)op = w0;
                *(s16x8*)(op + 8) = w1;
            }
        }
    }
}

// ---------------- K3: proj GEMM + bias + residual + transpose-out ----------------
// 256 threads (4 waves), block = (b, h, f-pair, n-half): M=64 (32 w x 2 f),
// N=256, K=512. BK=32, ring-3 + 2-ahead counted vmcnt (proven protocol).
// LDS 60 KB -> 2 blocks/CU for cross-block latency cover. grid 2048.
__global__ __launch_bounds__(256, 2) void k_proj_out(
        const ushort_t* __restrict__ att, const ushort_t* __restrict__ wp,
        const float* __restrict__ bp, const float* __restrict__ x,
        float* __restrict__ out) {
    __shared__ __align__(16) char U[61440];   // A: 3x4096 @0, B: 3x16384 @12288
    int bid = blockIdx.x;
    int nh = bid & 1;
    int fp = (bid >> 1) & 7;
    int h = (bid >> 4) & 31;
    int b = bid >> 9;
    const int n0 = nh * 256;
    const int t = threadIdx.x;
    const int lane = t & 63;
    const int wv = t >> 6;          // 0..3 = N quarter
    const int l16 = lane & 15;
    const int lg = lane >> 4;
    size_t attbase = ((size_t)(b * 32 + h) * 32) * 16 + fp * 2;  // + w*16 + fl

    auto stA = [&](int buf, int ks) {
        int row = t >> 2, slot = t & 3;       // 64 rows x 4 slots = 256 units
        int w = row & 31, fl = row >> 5;
        const ushort_t* src = att + (attbase + (size_t)w * 16 + fl) * 512 + ks * 32 + ((slot ^ ((row >> 2) & 3)) << 3);
        gload16(src, (ushort_t*)(U + buf * 4096) + t * 8);
    };
    auto stB = [&](int buf, int ks) {
        #pragma unroll
        for (int i = 0; i < 4; ++i) {
            int u = t + i * 256;              // 1024 units (256 rows x 4 slots)
            int row = u >> 2, slot = u & 3;
            const ushort_t* src = wp + (size_t)(n0 + row) * 512 + ks * 32 + ((slot ^ ((row >> 2) & 3)) << 3);
            gload16(src, (ushort_t*)(U + 12288 + buf * 16384) + u * 8);
        }
    };

    f32x4 acc[4][4];
    #pragma unroll
    for (int m = 0; m < 4; ++m)
        #pragma unroll
        for (int n = 0; n < 4; ++n)
            acc[m][n] = (f32x4){0.f, 0.f, 0.f, 0.f};

    stA(0, 0); stB(0, 0);    // 5 loads
    stA(1, 1); stB(1, 1);    // 5 loads -> 10 in flight
    for (int ks = 0; ks < 16; ++ks) {
        int cur = ks % 3;
        if (ks < 14) {
            stA((ks + 2) % 3, ks + 2);
            stB((ks + 2) % 3, ks + 2);
            asm volatile("s_waitcnt vmcnt(10)" ::: "memory");
        } else if (ks == 14) {
            asm volatile("s_waitcnt vmcnt(5)" ::: "memory");
        } else {
            asm volatile("s_waitcnt vmcnt(0)" ::: "memory");
        }
        wg_barrier();
        s16x8 af[4], bf[4];
        #pragma unroll
        for (int mf = 0; mf < 4; ++mf) {
            int row = mf * 16 + l16;
            af[mf] = *(const s16x8*)((ushort_t*)(U + cur * 4096) + row * 32 + ((lg ^ ((row >> 2) & 3)) << 3));
        }
        #pragma unroll
        for (int nf = 0; nf < 4; ++nf) {
            int nrow = wv * 64 + nf * 16 + l16;
            bf[nf] = *(const s16x8*)((ushort_t*)(U + 12288 + cur * 16384) + nrow * 32 + ((lg ^ ((nrow >> 2) & 3)) << 3));
        }
        #pragma unroll
        for (int mf = 0; mf < 4; ++mf)
            #pragma unroll
            for (int nf = 0; nf < 4; ++nf)
                acc[mf][nf] = __builtin_amdgcn_mfma_f32_16x16x32_bf16(bf[nf], af[mf], acc[mf][nf], 0, 0, 0);
        wg_barrier();
    }

    // epilogue: direct stores, bias + residual fused (D: col l16 = M, row lg*4+r = N)
    size_t obase = (size_t)b * SB + (size_t)(fp * 2) * SF + h * 32;
    #pragma unroll
    for (int mf = 0; mf < 4; ++mf) {
        int m = mf * 16 + l16;
        int w = m & 31, fl = m >> 5;
        size_t base_m = obase + (size_t)fl * SF + w;
        #pragma unroll
        for (int nf = 0; nf < 4; ++nf) {
            int col0 = n0 + wv * 64 + nf * 16 + lg * 4;
            #pragma unroll
            for (int r = 0; r < 4; ++r) {
                int col = col0 + r;
                size_t a = base_m + (size_t)col * SC;
                out[a] = acc[mf][nf][r] + bp[col] + x[a];
            }
        }
    }
}

extern "C" void kernel_launch(void* const* d_in, const int* in_sizes, int n_in,
                              void* d_out, int out_size, void* d_ws, size_t ws_size,
                              hipStream_t stream) {
    const float* x     = (const float*)d_in[0];
    const float* wqkv  = (const float*)d_in[1];
    const float* wproj = (const float*)d_in[2];
    const float* bproj = (const float*)d_in[3];
    const float* rb    = (const float*)d_in[4];
    const float* lng   = (const float*)d_in[5];
    const float* lnb   = (const float*)d_in[6];
    float* out = (float*)d_out;
    char* ws = (char*)d_ws;
    ushort_t* xn   = (ushort_t*)(ws);                  // 64 MB
    ushort_t* att  = (ushort_t*)(ws + 67108864);       // 64 MB
    ushort_t* wq16 = (ushort_t*)(ws + 134217728);      // 1.5 MB
    ushort_t* wp16 = (ushort_t*)(ws + 135790592);      // 0.5 MB

    k_cvt<<<3072, 256, 0, stream>>>(wqkv, 1536 * 512, wproj, 512 * 512, wq16, wp16);
    k_ln_transpose<<<2048, 256, 0, stream>>>(x, lng, lnb, xn);
    k_qkv_attn<<<512, 512, 0, stream>>>(xn, wq16, rb, att);
    k_proj_out<<<2048, 256, 0, stream>>>(att, wp16, bproj, x, out);
}

// Round 15
// 321.215 us; speedup vs baseline: 1.5259x; 1.0199x over previous
//
#include <hip/hip_runtime.h>

typedef unsigned short ushort_t;
typedef __attribute__((ext_vector_type(4))) float f32x4;
typedef __attribute__((ext_vector_type(8))) short s16x8;
typedef __attribute__((ext_vector_type(4))) short s16x4;

#define SB 8388608   // x batch stride (512*16*32*32)
#define SC 16384     // x channel stride (16*32*32)
#define SF 1024      // x frame stride (32*32)

static __device__ __forceinline__ float bf2f(ushort_t u) {
    union { float f; unsigned int i; } x; x.i = ((unsigned int)u) << 16; return x.f;
}
static __device__ __forceinline__ ushort_t f2bf(float f) {
    union { float f; unsigned int i; } x; x.f = f;
    unsigned int u = x.i;
    unsigned int r = (u + 0x7FFFu + ((u >> 16) & 1u)) >> 16;
    return (ushort_t)r;
}

static __device__ __forceinline__ void gload16(const void* g, void* l) {
    __builtin_amdgcn_global_load_lds(
        (const __attribute__((address_space(1))) unsigned int*)g,
        (__attribute__((address_space(3))) unsigned int*)l, 16, 0, 0);
}

// raw barrier: no implicit vmcnt(0) drain
static __device__ __forceinline__ void wg_barrier() {
    asm volatile("" ::: "memory");
    __builtin_amdgcn_s_barrier();
    asm volatile("" ::: "memory");
}

// ---------------- K0: convert weights to bf16 ----------------
__global__ void k_cvt(const float* __restrict__ a, int n1,
                      const float* __restrict__ b, int n2,
                      ushort_t* __restrict__ o1, ushort_t* __restrict__ o2) {
    int i = blockIdx.x * blockDim.x + threadIdx.x;
    if (i < n1) o1[i] = f2bf(a[i]);
    if (i < n2) o2[i] = f2bf(b[i]);
}

// ---------------- K1: LayerNorm + transpose -> xn (65536 x 512) bf16 ----------------
__global__ __launch_bounds__(256) void k_ln_transpose(
        const float* __restrict__ x, const float* __restrict__ g,
        const float* __restrict__ bta, ushort_t* __restrict__ xn) {
    __shared__ float tile[32 * 513];
    __shared__ float gg[512];
    __shared__ float bb[512];
    int bid = blockIdx.x;
    int b = bid >> 9;
    int f = (bid >> 5) & 15;
    int h = bid & 31;
    int t = threadIdx.x;
    for (int c = t; c < 512; c += 256) { gg[c] = g[c]; bb[c] = bta[c]; }
    const float* xp = x + (size_t)b * SB + (size_t)f * SF + h * 32;
    int wq4 = (t & 7) * 4;
    int c0 = t >> 3;
    for (int it = 0; it < 16; ++it) {
        int c = c0 + it * 32;
        f32x4 v = *(const f32x4*)(xp + (size_t)c * SC + wq4);
        tile[(wq4 + 0) * 513 + c] = v[0];
        tile[(wq4 + 1) * 513 + c] = v[1];
        tile[(wq4 + 2) * 513 + c] = v[2];
        tile[(wq4 + 3) * 513 + c] = v[3];
    }
    __syncthreads();
    int lane = t & 63;
    int wave = t >> 6;
    for (int wi = 0; wi < 8; ++wi) {
        int ww = wave * 8 + wi;
        float s = 0.f, s2 = 0.f;
        #pragma unroll
        for (int j = 0; j < 8; ++j) {
            float v = tile[ww * 513 + lane + j * 64];
            s += v; s2 += v * v;
        }
        #pragma unroll
        for (int off = 32; off; off >>= 1) { s += __shfl_xor(s, off); s2 += __shfl_xor(s2, off); }
        float mean = s * (1.f / 512.f);
        float var = s2 * (1.f / 512.f) - mean * mean;
        float rstd = rsqrtf(var + 1e-5f);
        size_t row = ((size_t)((b * 32 + h) * 32 + ww)) * 16 + f;
        ushort_t* op = xn + row * 512 + lane * 8;
        union { ushort_t a[8]; s16x8 v; } u;
        #pragma unroll
        for (int j = 0; j < 8; ++j) {
            int c = lane * 8 + j;
            float v = tile[ww * 513 + c];
            u.a[j] = f2bf((v - mean) * rstd * gg[c] + bb[c]);
        }
        *(s16x8*)op = u.v;
    }
}

// ---------------- K2: fused QKV GEMM + attention (round-7 proven: 170 us) ----
// block = 8 sequences (128 rows), 512 threads (8 waves). BK=64, 3-deep
// staging ring with 2-ahead prefetch + counted vmcnt (no drain-0 in loop).
__global__ __launch_bounds__(512) void k_qkv_attn(
        const ushort_t* __restrict__ xn, const ushort_t* __restrict__ wq,
        const float* __restrict__ rb, ushort_t* __restrict__ att) {
    __shared__ __align__(16) char U[122880];
    // staging ring: A buf i @ U + i*16384 (i<3); B buf i @ U + 49152 + i*24576
    // attention layout (aliases ring):
    ushort_t* qsm = (ushort_t*)(U);            // 16384 B [128 m][64 d] swz
    ushort_t* ksm = (ushort_t*)(U + 16384);    // 16384 B
    ushort_t* vT  = (ushort_t*)(U + 32768);    // 17408 B [64 d][136 m]

    const int t = threadIdx.x;
    const int lane = t & 63;
    const int wv = t >> 6;
    const int l16 = lane & 15;
    const int lg = lane >> 4;
    const int m0 = blockIdx.x * 128;
    const int wm = wv >> 2;   // 0..1  (M half)
    const int wn = wv & 3;    // 0..3  (N quarter)
    ushort_t* psw = ksm + wv * 1024;   // per-wave P scratch
    ushort_t* olw = qsm + wv * 1024;   // per-wave out-stage scratch

    // A K-slice: 128 rows x 64 K (16384 B = 1024 x 16B), 2 loads/thread
    auto stageA = [&](int buf, int kb) {
        ushort_t* dst = (ushort_t*)(U + buf * 16384);
        #pragma unroll
        for (int it = 0; it < 2; ++it) {
            int f = t + it * 512;
            int row = f >> 3, slot = f & 7;
            const ushort_t* src = xn + (size_t)(m0 + row) * 512 + kb * 64 + ((slot ^ (row & 7)) << 3);
            gload16(src, dst + f * 8);
        }
    };
    // B K-slice: 192 rows x 64 K (24576 B = 1536 x 16B), 3 loads/thread
    auto stageB = [&](int buf, int kb, int h) {
        ushort_t* dst = (ushort_t*)(U + 49152 + buf * 24576);
        #pragma unroll
        for (int it = 0; it < 3; ++it) {
            int f = t + it * 512;
            int brow = f >> 3, slot = f & 7;
            int wrow = (brow >> 6) * 512 + h * 64 + (brow & 63);
            const ushort_t* src = wq + (size_t)wrow * 512 + kb * 64 + ((slot ^ (brow & 7)) << 3);
            gload16(src, dst + f * 8);
        }
    };

    for (int h = 0; h < 8; ++h) {
        __syncthreads();                     // attn of h-1 fully done before ring reuse
        stageA(0, 0); stageB(0, 0, h);       // kb=0  (5 loads)
        stageA(1, 1); stageB(1, 1, h);       // kb=1  (5 loads) -> 10 in flight

        f32x4 acc[4][3];
        #pragma unroll
        for (int a1 = 0; a1 < 4; ++a1)
            #pragma unroll
            for (int a2 = 0; a2 < 3; ++a2)
                acc[a1][a2] = (f32x4){0.f, 0.f, 0.f, 0.f};

        for (int kb = 0; kb < 8; ++kb) {
            int cur = kb % 3;
            if (kb < 6) {
                stageA((kb + 2) % 3, kb + 2);
                stageB((kb + 2) % 3, kb + 2, h);
                asm volatile("s_waitcnt vmcnt(10)" ::: "memory");  // stage(kb) done
            } else if (kb == 6) {
                asm volatile("s_waitcnt vmcnt(5)" ::: "memory");
            } else {
                asm volatile("s_waitcnt vmcnt(0)" ::: "memory");
            }
            wg_barrier();                    // all waves' stage(kb) visible
            const ushort_t* Ac = (const ushort_t*)(U + cur * 16384);
            const ushort_t* Bc = (const ushort_t*)(U + 49152 + cur * 24576);
            #pragma unroll
            for (int kk = 0; kk < 2; ++kk) {
                int koff = kk * 64 + lg * 16;   // byte offset within 128B row
                s16x8 af[4], bf[3];
                #pragma unroll
                for (int mf = 0; mf < 4; ++mf) {
                    int row = wm * 64 + mf * 16 + l16;
                    af[mf] = *(const s16x8*)&Ac[row * 64 + ((koff ^ ((row & 7) << 4)) >> 1)];
                }
                #pragma unroll
                for (int nf = 0; nf < 3; ++nf) {
                    int nrow = wn * 48 + nf * 16 + l16;
                    bf[nf] = *(const s16x8*)&Bc[nrow * 64 + ((koff ^ ((nrow & 7) << 4)) >> 1)];
                }
                #pragma unroll
                for (int mf = 0; mf < 4; ++mf)
                    #pragma unroll
                    for (int nf = 0; nf < 3; ++nf)
                        acc[mf][nf] = __builtin_amdgcn_mfma_f32_16x16x32_bf16(af[mf], bf[nf], acc[mf][nf], 0, 0, 0);
            }
            wg_barrier();                    // readers done before ring slot reuse
        }

        // C-write: q/k swizzled [m][d], V transposed [d][m] (aliases ring)
        #pragma unroll
        for (int mf = 0; mf < 4; ++mf) {
            int mbase = wm * 64 + mf * 16 + lg * 4;
            #pragma unroll
            for (int nf = 0; nf < 3; ++nf) {
                int nn = wn * 48 + nf * 16 + l16;
                int seg = nn >> 6;
                int d = nn & 63;
                if (seg == 2) {
                    union { s16x4 v; ushort_t a[4]; } pk;
                    #pragma unroll
                    for (int r = 0; r < 4; ++r) pk.a[r] = f2bf(acc[mf][nf][r]);
                    *(s16x4*)&vT[d * 136 + mbase] = pk.v;
                } else {
                    ushort_t* dst = seg ? ksm : qsm;
                    #pragma unroll
                    for (int r = 0; r < 4; ++r) {
                        int m = mbase + r;
                        dst[m * 64 + (d ^ ((m & 7) << 3))] = f2bf(acc[mf][nf][r]);
                    }
                }
            }
        }
        __syncthreads();

        // ---- attention: wave wv handles sequence wv (16 rows) ----
        {
            int arow = wv * 16 + l16;
            int sw = (arow & 7) << 4;
            f32x4 sacc = (f32x4){0.f, 0.f, 0.f, 0.f};
            #pragma unroll
            for (int kk = 0; kk < 2; ++kk) {
                int off = kk * 64 + lg * 16;
                s16x8 ka = *(const s16x8*)&ksm[arow * 64 + ((off ^ sw) >> 1)];
                s16x8 qb = *(const s16x8*)&qsm[arow * 64 + ((off ^ sw) >> 1)];
                sacc = __builtin_amdgcn_mfma_f32_16x16x32_bf16(ka, qb, sacc, 0, 0, 0);
            }
            // lane holds S[j][i]: i = l16, j = lg*4+r
            const float* rbp = rb + l16 * 64 + lg * 4;
            float p[4];
            float mx = -1e30f;
            #pragma unroll
            for (int r = 0; r < 4; ++r) {
                p[r] = sacc[r] * 0.125f + rbp[r];
                mx = fmaxf(mx, p[r]);
            }
            mx = fmaxf(mx, __shfl_xor(mx, 16));
            mx = fmaxf(mx, __shfl_xor(mx, 32));
            float sum = 0.f;
            #pragma unroll
            for (int r = 0; r < 4; ++r) { p[r] = __expf(p[r] - mx); sum += p[r]; }
            sum += __shfl_xor(sum, 16);
            sum += __shfl_xor(sum, 32);
            float inv = 1.f / sum;
            {
                union { s16x4 v; ushort_t a[4]; } pk;
                #pragma unroll
                for (int r = 0; r < 4; ++r) pk.a[r] = f2bf(p[r] * inv);
                *(s16x4*)&psw[l16 * 16 + lg * 4] = pk.v;   // P[i][j]
            }
            asm volatile("s_waitcnt lgkmcnt(0)" ::: "memory");
            // PV: A = P rows i (j padded to 32 with zeros), B = vT rows d
            s16x8 ap = (s16x8){0, 0, 0, 0, 0, 0, 0, 0};
            if (lg < 2) ap = *(const s16x8*)&psw[l16 * 16 + lg * 8];
            int jj = (lg < 2) ? lg * 8 : 0;
            f32x4 ov[4];
            #pragma unroll
            for (int ff = 0; ff < 4; ++ff) {
                int d = ff * 16 + l16;
                s16x8 bv = *(const s16x8*)&vT[d * 136 + wv * 16 + jj];
                ov[ff] = __builtin_amdgcn_mfma_f32_16x16x32_bf16(ap, bv, (f32x4){0.f, 0.f, 0.f, 0.f}, 0, 0, 0);
            }
            // stage output through this wave's private LDS rows for 16B stores
            #pragma unroll
            for (int ff = 0; ff < 4; ++ff)
                #pragma unroll
                for (int r = 0; r < 4; ++r)
                    olw[(lg * 4 + r) * 64 + ff * 16 + l16] = f2bf(ov[ff][r]);
            asm volatile("s_waitcnt lgkmcnt(0)" ::: "memory");
            {
                int i2 = lane >> 2;
                int c2 = (lane & 3) * 16;
                s16x8 w0 = *(const s16x8*)&olw[i2 * 64 + c2];
                s16x8 w1 = *(const s16x8*)&olw[i2 * 64 + c2 + 8];
                ushort_t* op = att + (size_t)(m0 + wv * 16 + i2) * 512 + h * 64 + c2;
                *(s16x8*)op = w0;
                *(s16x8*)(op + 8) = w1;
            }
        }
    }
}

// ---------------- K3: proj GEMM + bias + residual + transpose-out ----------------
// block = (b, h, f-quad, n-half): M=128 rows, N=256, K=512. 512 threads.
// BK=32, 3-deep ring + counted vmcnt. LDS 72 KB. (proven r7/r12)
__global__ __launch_bounds__(512, 2) void k_proj_out(
        const ushort_t* __restrict__ att, const ushort_t* __restrict__ wp,
        const float* __restrict__ bp, const float* __restrict__ x,
        float* __restrict__ out) {
    __shared__ __align__(16) char U[73728];   // A: 3x8192 @0, B: 3x16384 @24576
    int bid = blockIdx.x;
    int nh = bid & 1;
    int fq = (bid >> 1) & 3;
    int h = (bid >> 3) & 31;
    int b = bid >> 8;
    const int n0 = nh * 256;
    const int t = threadIdx.x;
    const int lane = t & 63;
    const int wv = t >> 6;
    const int l16 = lane & 15;
    const int lg = lane >> 4;
    const int wm = wv >> 2;   // 0..1
    const int wn = wv & 3;    // 0..3
    size_t attbase = ((size_t)(b * 32 + h) * 32) * 16 + fq * 4;  // + w*16 + fl

    auto stA = [&](int buf, int ks) {
        int row = t >> 2, slot = t & 3;
        int w = row & 31, fl = row >> 5;
        const ushort_t* src = att + (attbase + (size_t)w * 16 + fl) * 512 + ks * 32 + ((slot ^ ((row >> 2) & 3)) << 3);
        gload16(src, (ushort_t*)(U + buf * 8192) + t * 8);
    };
    auto stB = [&](int buf, int ks) {
        #pragma unroll
        for (int i = 0; i < 2; ++i) {
            int u = t + i * 512;      // 1024 units (256 rows x 4 slots)
            int row = u >> 2, slot = u & 3;
            const ushort_t* src = wp + (size_t)(n0 + row) * 512 + ks * 32 + ((slot ^ ((row >> 2) & 3)) << 3);
            gload16(src, (ushort_t*)(U + 24576 + buf * 16384) + u * 8);
        }
    };

    f32x4 acc[4][4];
    #pragma unroll
    for (int m = 0; m < 4; ++m)
        #pragma unroll
        for (int n = 0; n < 4; ++n)
            acc[m][n] = (f32x4){0.f, 0.f, 0.f, 0.f};

    stA(0, 0); stB(0, 0);    // 3 loads
    stA(1, 1); stB(1, 1);    // 3 loads -> 6 in flight
    for (int ks = 0; ks < 16; ++ks) {
        int cur = ks % 3;
        if (ks < 14) {
            stA((ks + 2) % 3, ks + 2);
            stB((ks + 2) % 3, ks + 2);
            asm volatile("s_waitcnt vmcnt(6)" ::: "memory");
        } else if (ks == 14) {
            asm volatile("s_waitcnt vmcnt(3)" ::: "memory");
        } else {
            asm volatile("s_waitcnt vmcnt(0)" ::: "memory");
        }
        wg_barrier();
        s16x8 af[4], bf[4];
        #pragma unroll
        for (int mf = 0; mf < 4; ++mf) {
            int row = wm * 64 + mf * 16 + l16;
            af[mf] = *(const s16x8*)((ushort_t*)(U + cur * 8192) + row * 32 + ((lg ^ ((row >> 2) & 3)) << 3));
        }
        #pragma unroll
        for (int nf = 0; nf < 4; ++nf) {
            int nrow = wn * 64 + nf * 16 + l16;
            bf[nf] = *(const s16x8*)((ushort_t*)(U + 24576 + cur * 16384) + nrow * 32 + ((lg ^ ((nrow >> 2) & 3)) << 3));
        }
        #pragma unroll
        for (int mf = 0; mf < 4; ++mf)
            #pragma unroll
            for (int nf = 0; nf < 4; ++nf)
                acc[mf][nf] = __builtin_amdgcn_mfma_f32_16x16x32_bf16(bf[nf], af[mf], acc[mf][nf], 0, 0, 0);
        wg_barrier();
    }

    // epilogue: direct stores, bias + residual fused (D: col l16 = M, row lg*4+r = N)
    size_t obase = (size_t)b * SB + (size_t)(fq * 4) * SF + h * 32;
    #pragma unroll
    for (int mf = 0; mf < 4; ++mf) {
        int m = wm * 64 + mf * 16 + l16;
        int w = m & 31, fl = m >> 5;
        size_t base_m = obase + (size_t)fl * SF + w;
        #pragma unroll
        for (int nf = 0; nf < 4; ++nf) {
            int col0 = n0 + wn * 64 + nf * 16 + lg * 4;
            #pragma unroll
            for (int r = 0; r < 4; ++r) {
                int col = col0 + r;
                size_t a = base_m + (size_t)col * SC;
                out[a] = acc[mf][nf][r] + bp[col] + x[a];
            }
        }
    }
}

extern "C" void kernel_launch(void* const* d_in, const int* in_sizes, int n_in,
                              void* d_out, int out_size, void* d_ws, size_t ws_size,
                              hipStream_t stream) {
    const float* x     = (const float*)d_in[0];
    const float* wqkv  = (const float*)d_in[1];
    const float* wproj = (const float*)d_in[2];
    const float* bproj = (const float*)d_in[3];
    const float* rb    = (const float*)d_in[4];
    const float* lng   = (const float*)d_in[5];
    const float* lnb   = (const float*)d_in[6];
    float* out = (float*)d_out;
    char* ws = (char*)d_ws;
    ushort_t* xn   = (ushort_t*)(ws);                  // 64 MB
    ushort_t* att  = (ushort_t*)(ws + 67108864);       // 64 MB
    ushort_t* wq16 = (ushort_t*)(ws + 134217728);      // 1.5 MB
    ushort_t* wp16 = (ushort_t*)(ws + 135790592);      // 0.5 MB

    k_cvt<<<3072, 256, 0, stream>>>(wqkv, 1536 * 512, wproj, 512 * 512, wq16, wp16);
    k_ln_transpose<<<2048, 256, 0, stream>>>(x, lng, lnb, xn);
    k_qkv_attn<<<512, 512, 0, stream>>>(xn, wq16, rb, att);
    k_proj_out<<<1024, 512, 0, stream>>>(att, wp16, bproj, x, out);
}